// Round 2
// baseline (2226.212 us; speedup 1.0000x reference)
//
#include <hip/hip_runtime.h>
#include <cstdint>

#define NF 128

__device__ __forceinline__ float2 ld2(const float* p) {
    return *reinterpret_cast<const float2*>(p);
}

// C[N,128] = X[N,128] @ W[128,128] (+ addb) (+ bias) (relu)
// One wave per 4 rows; lane owns cols 2*lane, 2*lane+1. X row broadcast via shfl.
template<int RELU, int HAS_ADD, int HAS_BIAS>
__global__ __launch_bounds__(256) void gemm128_k(
    const float* __restrict__ X, const float* __restrict__ W,
    const float* __restrict__ addb, const float* __restrict__ bias,
    float* __restrict__ C, int N)
{
    const int lane = threadIdx.x & 63;
    const int wid  = threadIdx.x >> 6;
    const int rowBase = (blockIdx.x * 4 + wid) * 4;   // 16 rows per block
    if (rowBase >= N) return;

    float2 x2[4];
#pragma unroll
    for (int r = 0; r < 4; ++r)
        x2[r] = ld2(&X[(size_t)(rowBase + r) * NF + lane * 2]);

    float2 acc[4];
#pragma unroll
    for (int r = 0; r < 4; ++r) { acc[r].x = 0.f; acc[r].y = 0.f; }

#pragma unroll 8
    for (int kk = 0; kk < 64; ++kk) {
        float2 w0 = ld2(&W[(2*kk)     * NF + lane*2]);
        float2 w1 = ld2(&W[(2*kk + 1) * NF + lane*2]);
#pragma unroll
        for (int r = 0; r < 4; ++r) {
            float xa = __shfl(x2[r].x, kk);   // X[row][2kk]
            float xb = __shfl(x2[r].y, kk);   // X[row][2kk+1]
            acc[r].x = fmaf(xa, w0.x, fmaf(xb, w1.x, acc[r].x));
            acc[r].y = fmaf(xa, w0.y, fmaf(xb, w1.y, acc[r].y));
        }
    }

#pragma unroll
    for (int r = 0; r < 4; ++r) {
        float2 v = acc[r];
        if (HAS_ADD) {
            float2 a = ld2(&addb[(size_t)(rowBase + r) * NF + lane*2]);
            v.x += a.x; v.y += a.y;
        }
        if (HAS_BIAS) {
            float2 b = ld2(&bias[lane*2]);
            v.x += b.x; v.y += b.y;
        }
        if (RELU) { v.x = fmaxf(v.x, 0.f); v.y = fmaxf(v.y, 0.f); }
        *reinterpret_cast<float2*>(&C[(size_t)(rowBase + r) * NF + lane*2]) = v;
    }
}

// agg[dst] += T[src] for each edge. One wave per edge, float2 per lane.
__global__ __launch_bounds__(256) void scatter_add_k(
    const float* __restrict__ T, const int* __restrict__ ei,
    float* __restrict__ agg, int E)
{
    int gid  = blockIdx.x * 256 + threadIdx.x;
    int e    = gid >> 6;
    int lane = gid & 63;
    if (e >= E) return;
    int s = ei[e];
    int d = ei[E + e];
    float2 v = ld2(&T[(size_t)s * NF + lane*2]);
    float* p = &agg[(size_t)d * NF + lane*2];
    unsafeAtomicAdd(p,     v.x);
    unsafeAtomicAdd(p + 1, v.y);
}

// Per edge: mean = relu(P[s]+Q[d]) . Wm2 + bm2 ; var = exp(0.5*(relu(R[s]+S[d]) . Wv2 + bv2))
__global__ __launch_bounds__(256) void edge_head_k(
    const float* __restrict__ P, const float* __restrict__ Q,
    const float* __restrict__ R, const float* __restrict__ S,
    const int* __restrict__ ei,
    const float* __restrict__ Wm2, const float* __restrict__ Wv2,
    const float* __restrict__ bm2, const float* __restrict__ bv2,
    float* __restrict__ mean_out, float* __restrict__ var_out, int E)
{
    int gid  = blockIdx.x * 256 + threadIdx.x;
    int e    = gid >> 6;
    int lane = gid & 63;
    if (e >= E) return;
    int s = ei[e];
    int d = ei[E + e];

    float2 p = ld2(&P[(size_t)s * NF + lane*2]);
    float2 q = ld2(&Q[(size_t)d * NF + lane*2]);
    float2 r = ld2(&R[(size_t)s * NF + lane*2]);
    float2 t = ld2(&S[(size_t)d * NF + lane*2]);

    float ux = fmaxf(p.x + q.x, 0.f);
    float uy = fmaxf(p.y + q.y, 0.f);
    float vx = fmaxf(r.x + t.x, 0.f);
    float vy = fmaxf(r.y + t.y, 0.f);

    float2 wm = ld2(&Wm2[lane*2]);
    float2 wv = ld2(&Wv2[lane*2]);

    float pm = fmaf(ux, wm.x, uy * wm.y);
    float pv = fmaf(vx, wv.x, vy * wv.y);

#pragma unroll
    for (int off = 32; off > 0; off >>= 1) {
        pm += __shfl_xor(pm, off);
        pv += __shfl_xor(pv, off);
    }
    if (lane == 0) {
        mean_out[e] = pm + bm2[0];
        var_out[e]  = expf(0.5f * (pv + bv2[0]));
    }
}

extern "C" void kernel_launch(void* const* d_in, const int* in_sizes, int n_in,
                              void* d_out, int out_size, void* d_ws, size_t ws_size,
                              hipStream_t stream)
{
    const float* x       = (const float*)d_in[0];
    const int*   ei      = (const int*)d_in[1];
    const float* W1_rel  = (const float*)d_in[2];
    const float* b1      = (const float*)d_in[3];
    const float* W1_root = (const float*)d_in[4];
    const float* W2_rel  = (const float*)d_in[5];
    const float* b2      = (const float*)d_in[6];
    const float* W2_root = (const float*)d_in[7];
    const float* Wm1     = (const float*)d_in[8];
    const float* bm1     = (const float*)d_in[9];
    const float* Wm2     = (const float*)d_in[10];
    const float* bm2     = (const float*)d_in[11];
    const float* Wv1     = (const float*)d_in[12];
    const float* bv1     = (const float*)d_in[13];
    const float* Wv2     = (const float*)d_in[14];
    const float* bv2     = (const float*)d_in[15];

    const int N = in_sizes[0] / NF;   // 50000
    const int E = in_sizes[1] / 2;    // 800000

    const size_t SZ = (size_t)N * NF * sizeof(float);   // 25.6 MB
    char* base = (char*)d_ws;
    float* A  = (float*)(base);            // t1 / t2 / h2
    float* B  = (float*)(base + SZ);       // agg1 / agg2 / P
    float* Cb = (float*)(base + 2*SZ);     // h1 / Q
    float* D  = (float*)(base + 3*SZ);     // R
    float* Eb = (float*)(base + 4*SZ);     // S

    float* out_mean = (float*)d_out;
    float* out_var  = out_mean + E;

    dim3 blk(256);
    dim3 gemmGrid((N + 15) / 16);                 // 3125
    dim3 edgeGrid((unsigned)(((size_t)E * 64 + 255) / 256));  // 200000

    // ---- conv1: h1 = relu(scatter(x@W1_rel) + b1 + x@W1_root)
    hipLaunchKernelGGL((gemm128_k<0,0,0>), gemmGrid, blk, 0, stream,
                       x, W1_rel, nullptr, nullptr, A, N);
    hipMemsetAsync(B, 0, SZ, stream);
    hipLaunchKernelGGL(scatter_add_k, edgeGrid, blk, 0, stream, A, ei, B, E);
    hipLaunchKernelGGL((gemm128_k<1,1,1>), gemmGrid, blk, 0, stream,
                       x, W1_root, B, b1, Cb, N);

    // ---- conv2: h2 = relu(scatter(h1@W2_rel) + b2 + h1@W2_root)  -> A
    hipLaunchKernelGGL((gemm128_k<0,0,0>), gemmGrid, blk, 0, stream,
                       Cb, W2_rel, nullptr, nullptr, A, N);
    hipMemsetAsync(B, 0, SZ, stream);
    hipLaunchKernelGGL(scatter_add_k, edgeGrid, blk, 0, stream, A, ei, B, E);
    hipLaunchKernelGGL((gemm128_k<1,1,1>), gemmGrid, blk, 0, stream,
                       Cb, W2_root, B, b2, A, N);

    // ---- per-node head precompute: P,Q (mean head), R,S (logvar head)
    hipLaunchKernelGGL((gemm128_k<0,0,1>), gemmGrid, blk, 0, stream,
                       A, Wm1,           nullptr, bm1, B, N);       // P = h2@Wm1_top + bm1
    hipLaunchKernelGGL((gemm128_k<0,0,0>), gemmGrid, blk, 0, stream,
                       A, Wm1 + NF*NF,   nullptr, nullptr, Cb, N);  // Q = h2@Wm1_bot
    hipLaunchKernelGGL((gemm128_k<0,0,1>), gemmGrid, blk, 0, stream,
                       A, Wv1,           nullptr, bv1, D, N);       // R = h2@Wv1_top + bv1
    hipLaunchKernelGGL((gemm128_k<0,0,0>), gemmGrid, blk, 0, stream,
                       A, Wv1 + NF*NF,   nullptr, nullptr, Eb, N);  // S = h2@Wv1_bot

    // ---- per-edge epilogue
    hipLaunchKernelGGL(edge_head_k, edgeGrid, blk, 0, stream,
                       B, Cb, D, Eb, ei, Wm2, Wv2, bm2, bv2,
                       out_mean, out_var, E);
}

// Round 5
// 1113.965 us; speedup vs baseline: 1.9985x; 1.9985x over previous
//
#include <hip/hip_runtime.h>
#include <cstdint>

#define NF 128

__device__ __forceinline__ float2 ld2(const float* p) {
    return *reinterpret_cast<const float2*>(p);
}
__device__ __forceinline__ void st2(float* p, float2 v) {
    *reinterpret_cast<float2*>(p) = v;
}

// ---------------- CSR build ----------------

__global__ __launch_bounds__(256) void count_k(const int* __restrict__ ei,
                                               int* __restrict__ deg, int E)
{
    int e = blockIdx.x * 256 + threadIdx.x;
    if (e >= E) return;
    atomicAdd(&deg[ei[E + e]], 1);
}

// single-block exclusive scan over deg[N] -> rowptr[N+1], cursor[N]
__global__ __launch_bounds__(1024) void scan_k(const int* __restrict__ deg,
                                               int* __restrict__ rowptr,
                                               int* __restrict__ cursor, int N)
{
    __shared__ int ssum[1024];
    int tid = threadIdx.x;
    int chunk = (N + 1023) / 1024;
    int beg = tid * chunk;
    int end = min(beg + chunk, N);
    int s = 0;
    for (int i = beg; i < end; ++i) s += deg[i];
    ssum[tid] = s;
    __syncthreads();
    for (int off = 1; off < 1024; off <<= 1) {
        int v = (tid >= off) ? ssum[tid - off] : 0;
        __syncthreads();
        ssum[tid] += v;
        __syncthreads();
    }
    int run = (tid == 0) ? 0 : ssum[tid - 1];
    for (int i = beg; i < end; ++i) {
        rowptr[i] = run;
        cursor[i] = run;
        run += deg[i];
    }
    if (end == N) rowptr[N] = run;   // threads with empty chunks also write total E
}

__global__ __launch_bounds__(256) void fill_k(const int* __restrict__ ei,
                                              int* __restrict__ cursor,
                                              int* __restrict__ srclist, int E)
{
    int e = blockIdx.x * 256 + threadIdx.x;
    if (e >= E) return;
    int s = ei[e];
    int d = ei[E + e];
    int pos = atomicAdd(&cursor[d], 1);
    srclist[pos] = s;
}

// ---------------- aggregation: AGG[i] = sum_{j in in(i)} X[j] ----------------
// one wave per node; lanes cooperatively stage 64 source indices, broadcast
// via shfl; each gather is one coalesced 512B row read.
__global__ __launch_bounds__(256) void agg_k(const float* __restrict__ X,
                                             const int* __restrict__ rowptr,
                                             const int* __restrict__ srclist,
                                             float* __restrict__ AGG, int N)
{
    int gid  = blockIdx.x * 256 + threadIdx.x;
    int node = gid >> 6;
    int lane = gid & 63;
    if (node >= N) return;
    int beg = rowptr[node];
    int end = rowptr[node + 1];

    float2 a0 = {0.f, 0.f}, a1 = {0.f, 0.f}, a2 = {0.f, 0.f}, a3 = {0.f, 0.f};
    for (int base = beg; base < end; base += 64) {
        int cnt = min(64, end - base);
        int myidx = (lane < cnt) ? srclist[base + lane] : 0;
        int j = 0;
        for (; j + 4 <= cnt; j += 4) {
            int s0 = __shfl(myidx, j);
            int s1 = __shfl(myidx, j + 1);
            int s2 = __shfl(myidx, j + 2);
            int s3 = __shfl(myidx, j + 3);
            float2 v0 = ld2(&X[(size_t)s0 * NF + lane * 2]);
            float2 v1 = ld2(&X[(size_t)s1 * NF + lane * 2]);
            float2 v2 = ld2(&X[(size_t)s2 * NF + lane * 2]);
            float2 v3 = ld2(&X[(size_t)s3 * NF + lane * 2]);
            a0.x += v0.x; a0.y += v0.y;
            a1.x += v1.x; a1.y += v1.y;
            a2.x += v2.x; a2.y += v2.y;
            a3.x += v3.x; a3.y += v3.y;
        }
        for (; j < cnt; ++j) {
            int s0 = __shfl(myidx, j);
            float2 v0 = ld2(&X[(size_t)s0 * NF + lane * 2]);
            a0.x += v0.x; a0.y += v0.y;
        }
    }
    float2 acc;
    acc.x = (a0.x + a1.x) + (a2.x + a3.x);
    acc.y = (a0.y + a1.y) + (a2.y + a3.y);
    st2(&AGG[(size_t)node * NF + lane * 2], acc);
}

// ---------------- fused dual GEMM: C = relu(A@Wa + B@Wb + bias) ----------------
__global__ __launch_bounds__(256) void dualgemm_k(
    const float* __restrict__ A, const float* __restrict__ Wa,
    const float* __restrict__ B, const float* __restrict__ Wb,
    const float* __restrict__ bias, float* __restrict__ C, int N)
{
    const int lane = threadIdx.x & 63;
    const int wid  = threadIdx.x >> 6;
    const int rowBase = (blockIdx.x * 4 + wid) * 4;
    if (rowBase >= N) return;

    float2 xa[4], xb[4];
#pragma unroll
    for (int r = 0; r < 4; ++r) {
        xa[r] = ld2(&A[(size_t)(rowBase + r) * NF + lane * 2]);
        xb[r] = ld2(&B[(size_t)(rowBase + r) * NF + lane * 2]);
    }
    float2 acc[4];
#pragma unroll
    for (int r = 0; r < 4; ++r) { acc[r].x = 0.f; acc[r].y = 0.f; }

#pragma unroll 4
    for (int kk = 0; kk < 64; ++kk) {
        float2 wa0 = ld2(&Wa[(2*kk)     * NF + lane*2]);
        float2 wa1 = ld2(&Wa[(2*kk + 1) * NF + lane*2]);
        float2 wb0 = ld2(&Wb[(2*kk)     * NF + lane*2]);
        float2 wb1 = ld2(&Wb[(2*kk + 1) * NF + lane*2]);
#pragma unroll
        for (int r = 0; r < 4; ++r) {
            float a0 = __shfl(xa[r].x, kk);
            float a1 = __shfl(xa[r].y, kk);
            float b0 = __shfl(xb[r].x, kk);
            float b1 = __shfl(xb[r].y, kk);
            acc[r].x = fmaf(a0, wa0.x, fmaf(a1, wa1.x, fmaf(b0, wb0.x, fmaf(b1, wb1.x, acc[r].x))));
            acc[r].y = fmaf(a0, wa0.y, fmaf(a1, wa1.y, fmaf(b0, wb0.y, fmaf(b1, wb1.y, acc[r].y))));
        }
    }

#pragma unroll
    for (int r = 0; r < 4; ++r) {
        float2 b = ld2(&bias[lane*2]);
        float2 v = acc[r];
        v.x = fmaxf(v.x + b.x, 0.f);
        v.y = fmaxf(v.y + b.y, 0.f);
        st2(&C[(size_t)(rowBase + r) * NF + lane*2], v);
    }
}

// ---------------- head GEMM: PR = [H@Wm1_top + bm1 | H@Wv1_top + bv1],
//                             QS = [H@Wm1_bot       | H@Wv1_bot      ] ----------------
__global__ __launch_bounds__(256) void headgemm_k(
    const float* __restrict__ H,
    const float* __restrict__ Wm1, const float* __restrict__ bm1,
    const float* __restrict__ Wv1, const float* __restrict__ bv1,
    float* __restrict__ PR, float* __restrict__ QS, int N)
{
    const int lane = threadIdx.x & 63;
    const int wid  = threadIdx.x >> 6;
    const int rowBase = (blockIdx.x * 4 + wid) * 4;
    if (rowBase >= N) return;

    float2 x2[4];
#pragma unroll
    for (int r = 0; r < 4; ++r)
        x2[r] = ld2(&H[(size_t)(rowBase + r) * NF + lane * 2]);

    float2 ap[4], aq[4], ar[4], as_[4];
#pragma unroll
    for (int r = 0; r < 4; ++r) {
        ap[r] = make_float2(0.f, 0.f); aq[r] = make_float2(0.f, 0.f);
        ar[r] = make_float2(0.f, 0.f); as_[r] = make_float2(0.f, 0.f);
    }

    const float* Wm1b = Wm1 + (size_t)NF * NF;   // bottom half rows 128..255
    const float* Wv1b = Wv1 + (size_t)NF * NF;

#pragma unroll 2
    for (int kk = 0; kk < 64; ++kk) {
        float2 wp0 = ld2(&Wm1 [(2*kk)   * NF + lane*2]);
        float2 wp1 = ld2(&Wm1 [(2*kk+1) * NF + lane*2]);
        float2 wq0 = ld2(&Wm1b[(2*kk)   * NF + lane*2]);
        float2 wq1 = ld2(&Wm1b[(2*kk+1) * NF + lane*2]);
        float2 wr0 = ld2(&Wv1 [(2*kk)   * NF + lane*2]);
        float2 wr1 = ld2(&Wv1 [(2*kk+1) * NF + lane*2]);
        float2 ws0 = ld2(&Wv1b[(2*kk)   * NF + lane*2]);
        float2 ws1 = ld2(&Wv1b[(2*kk+1) * NF + lane*2]);
#pragma unroll
        for (int r = 0; r < 4; ++r) {
            float h0 = __shfl(x2[r].x, kk);
            float h1 = __shfl(x2[r].y, kk);
            ap[r].x = fmaf(h0, wp0.x, fmaf(h1, wp1.x, ap[r].x));
            ap[r].y = fmaf(h0, wp0.y, fmaf(h1, wp1.y, ap[r].y));
            aq[r].x = fmaf(h0, wq0.x, fmaf(h1, wq1.x, aq[r].x));
            aq[r].y = fmaf(h0, wq0.y, fmaf(h1, wq1.y, aq[r].y));
            ar[r].x = fmaf(h0, wr0.x, fmaf(h1, wr1.x, ar[r].x));
            ar[r].y = fmaf(h0, wr0.y, fmaf(h1, wr1.y, ar[r].y));
            as_[r].x = fmaf(h0, ws0.x, fmaf(h1, ws1.x, as_[r].x));
            as_[r].y = fmaf(h0, ws0.y, fmaf(h1, ws1.y, as_[r].y));
        }
    }

    float2 bm = ld2(&bm1[lane*2]);
    float2 bv = ld2(&bv1[lane*2]);
#pragma unroll
    for (int r = 0; r < 4; ++r) {
        size_t row = (size_t)(rowBase + r) * (2 * NF);
        float2 p = ap[r]; p.x += bm.x; p.y += bm.y;
        float2 rr = ar[r]; rr.x += bv.x; rr.y += bv.y;
        st2(&PR[row + lane*2],      p);
        st2(&PR[row + NF + lane*2], rr);
        st2(&QS[row + lane*2],      aq[r]);
        st2(&QS[row + NF + lane*2], as_[r]);
    }
}

// ---------------- per-edge epilogue ----------------
__global__ __launch_bounds__(256) void edge_head_k(
    const float* __restrict__ PR, const float* __restrict__ QS,
    const int* __restrict__ ei,
    const float* __restrict__ Wm2, const float* __restrict__ Wv2,
    const float* __restrict__ bm2, const float* __restrict__ bv2,
    float* __restrict__ mean_out, float* __restrict__ var_out, int E)
{
    int gid  = blockIdx.x * 256 + threadIdx.x;
    int e    = gid >> 6;
    int lane = gid & 63;
    if (e >= E) return;
    int s = ei[e];
    int d = ei[E + e];

    size_t srow = (size_t)s * (2 * NF);
    size_t drow = (size_t)d * (2 * NF);
    float2 p = ld2(&PR[srow + lane*2]);
    float2 r = ld2(&PR[srow + NF + lane*2]);
    float2 q = ld2(&QS[drow + lane*2]);
    float2 t = ld2(&QS[drow + NF + lane*2]);

    float ux = fmaxf(p.x + q.x, 0.f);
    float uy = fmaxf(p.y + q.y, 0.f);
    float vx = fmaxf(r.x + t.x, 0.f);
    float vy = fmaxf(r.y + t.y, 0.f);

    float2 wm = ld2(&Wm2[lane*2]);
    float2 wv = ld2(&Wv2[lane*2]);

    float pm = fmaf(ux, wm.x, uy * wm.y);
    float pv = fmaf(vx, wv.x, vy * wv.y);

#pragma unroll
    for (int off = 32; off > 0; off >>= 1) {
        pm += __shfl_xor(pm, off);
        pv += __shfl_xor(pv, off);
    }
    if (lane == 0) {
        mean_out[e] = pm + bm2[0];
        var_out[e]  = expf(0.5f * (pv + bv2[0]));
    }
}

extern "C" void kernel_launch(void* const* d_in, const int* in_sizes, int n_in,
                              void* d_out, int out_size, void* d_ws, size_t ws_size,
                              hipStream_t stream)
{
    const float* x       = (const float*)d_in[0];
    const int*   ei      = (const int*)d_in[1];
    const float* W1_rel  = (const float*)d_in[2];
    const float* b1      = (const float*)d_in[3];
    const float* W1_root = (const float*)d_in[4];
    const float* W2_rel  = (const float*)d_in[5];
    const float* b2      = (const float*)d_in[6];
    const float* W2_root = (const float*)d_in[7];
    const float* Wm1     = (const float*)d_in[8];
    const float* bm1     = (const float*)d_in[9];
    const float* Wm2     = (const float*)d_in[10];
    const float* bm2     = (const float*)d_in[11];
    const float* Wv1     = (const float*)d_in[12];
    const float* bv1     = (const float*)d_in[13];
    const float* Wv2     = (const float*)d_in[14];
    const float* bv2     = (const float*)d_in[15];

    const int N = in_sizes[0] / NF;   // 50000
    const int E = in_sizes[1] / 2;    // 800000

    const size_t SZ = (size_t)N * NF * sizeof(float);   // 25.6 MB

    char* base = (char*)d_ws;
    // region0: 2*SZ  -> AGG1 / AGG2 (first SZ), later PR (full 2*SZ)
    // region1: 2*SZ  -> h1 (first SZ), later QS (full 2*SZ)
    // region2: SZ    -> h2
    float* reg0 = (float*)(base);
    float* reg1 = (float*)(base + 2 * SZ);
    float* h2   = (float*)(base + 4 * SZ);
    float* AGG  = reg0;
    float* h1   = reg1;
    float* PR   = reg0;
    float* QS   = reg1;

    char* csr = base + 5 * SZ;
    int* deg     = (int*)(csr);
    int* rowptr  = (int*)(csr + (size_t)(N + 64) * 4);
    int* cursor  = (int*)(csr + (size_t)(N + 64) * 8);
    int* srclist = (int*)(csr + (size_t)(N + 64) * 12);

    float* out_mean = (float*)d_out;
    float* out_var  = out_mean + E;

    dim3 blk(256);
    dim3 eGrid((E + 255) / 256);                         // 3125
    dim3 gemmGrid((N + 15) / 16);                        // 3125
    dim3 nodeGrid(((size_t)N * 64 + 255) / 256);         // 12500
    dim3 edgeGrid((unsigned)(((size_t)E * 64 + 255) / 256)); // 200000

    // ---- CSR build (once, reused by both convs)
    hipMemsetAsync(deg, 0, (size_t)N * 4, stream);
    hipLaunchKernelGGL(count_k, eGrid, blk, 0, stream, ei, deg, E);
    hipLaunchKernelGGL(scan_k, dim3(1), dim3(1024), 0, stream, deg, rowptr, cursor, N);
    hipLaunchKernelGGL(fill_k, eGrid, blk, 0, stream, ei, cursor, srclist, E);

    // ---- conv1: h1 = relu(segsum(x)@W1_rel + x@W1_root + b1)
    hipLaunchKernelGGL(agg_k, nodeGrid, blk, 0, stream, x, rowptr, srclist, AGG, N);
    hipLaunchKernelGGL(dualgemm_k, gemmGrid, blk, 0, stream,
                       AGG, W1_rel, x, W1_root, b1, h1, N);

    // ---- conv2: h2 = relu(segsum(h1)@W2_rel + h1@W2_root + b2)
    hipLaunchKernelGGL(agg_k, nodeGrid, blk, 0, stream, h1, rowptr, srclist, AGG, N);
    hipLaunchKernelGGL(dualgemm_k, gemmGrid, blk, 0, stream,
                       AGG, W2_rel, h1, W2_root, b2, h2, N);

    // ---- node-level head precompute (PR overwrites AGG, QS overwrites h1)
    hipLaunchKernelGGL(headgemm_k, gemmGrid, blk, 0, stream,
                       h2, Wm1, bm1, Wv1, bv1, PR, QS, N);

    // ---- per-edge epilogue
    hipLaunchKernelGGL(edge_head_k, edgeGrid, blk, 0, stream,
                       PR, QS, ei, Wm2, Wv2, bm2, bv2, out_mean, out_var, E);
}

// Round 6
// 980.326 us; speedup vs baseline: 2.2709x; 1.1363x over previous
//
#include <hip/hip_runtime.h>
#include <cstdint>

#define NF 128

typedef unsigned int uint;

__device__ __forceinline__ float2 ld2(const float* p) {
    return *reinterpret_cast<const float2*>(p);
}
__device__ __forceinline__ void st2(float* p, float2 v) {
    *reinterpret_cast<float2*>(p) = v;
}
// bf16 pair packed in a uint: elem0 = bits[15:0], elem1 = bits[31:16]
__device__ __forceinline__ float bflo(uint u) { return __uint_as_float(u << 16); }
__device__ __forceinline__ float bfhi(uint u) { return __uint_as_float(u & 0xffff0000u); }
__device__ __forceinline__ uint f2bf_rne(float f) {
    uint u = __float_as_uint(f);
    return (u + 0x7fffu + ((u >> 16) & 1u)) >> 16;   // round-nearest-even (no NaN here)
}
__device__ __forceinline__ uint pack2bf(float a, float b) {
    return f2bf_rne(a) | (f2bf_rne(b) << 16);
}

// ---------------- fp32 -> bf16 table cast ----------------
__global__ __launch_bounds__(256) void cast_bf16_k(const float* __restrict__ in,
                                                   uint* __restrict__ out, int npairs)
{
    int i = blockIdx.x * 256 + threadIdx.x;
    if (i >= npairs) return;
    float2 v = ld2(&in[(size_t)i * 2]);
    out[i] = pack2bf(v.x, v.y);
}

// ---------------- CSR build ----------------
__global__ __launch_bounds__(256) void count_k(const int* __restrict__ ei,
                                               int* __restrict__ deg, int E)
{
    int e = blockIdx.x * 256 + threadIdx.x;
    if (e >= E) return;
    atomicAdd(&deg[ei[E + e]], 1);
}

__global__ __launch_bounds__(1024) void scan_k(const int* __restrict__ deg,
                                               int* __restrict__ rowptr,
                                               int* __restrict__ cursor, int N)
{
    __shared__ int ssum[1024];
    int tid = threadIdx.x;
    int chunk = (N + 1023) / 1024;
    int beg = tid * chunk;
    int end = min(beg + chunk, N);
    int s = 0;
    for (int i = beg; i < end; ++i) s += deg[i];
    ssum[tid] = s;
    __syncthreads();
    for (int off = 1; off < 1024; off <<= 1) {
        int v = (tid >= off) ? ssum[tid - off] : 0;
        __syncthreads();
        ssum[tid] += v;
        __syncthreads();
    }
    int run = (tid == 0) ? 0 : ssum[tid - 1];
    for (int i = beg; i < end; ++i) {
        rowptr[i] = run;
        cursor[i] = run;
        run += deg[i];
    }
    if (end == N) rowptr[N] = run;
}

__global__ __launch_bounds__(256) void fill_k(const int* __restrict__ ei,
                                              int* __restrict__ cursor,
                                              int* __restrict__ srclist,
                                              int* __restrict__ eidlist, int E)
{
    int e = blockIdx.x * 256 + threadIdx.x;
    if (e >= E) return;
    int s = ei[e];
    int d = ei[E + e];
    int pos = atomicAdd(&cursor[d], 1);
    srclist[pos] = s;
    eidlist[pos] = e;
}

// ---------------- aggregation from bf16 table: AGG[i] = sum X[j] (fp32 out) ------
// one wave per node; per gathered row each lane loads 1 dword (2 bf16) = 256B/row.
__global__ __launch_bounds__(256) void agg_bf16_k(const uint* __restrict__ Xb,
                                                  const int* __restrict__ rowptr,
                                                  const int* __restrict__ srclist,
                                                  float* __restrict__ AGG, int N)
{
    int gid  = blockIdx.x * 256 + threadIdx.x;
    int node = gid >> 6;
    int lane = gid & 63;
    if (node >= N) return;
    int beg = rowptr[node];
    int end = rowptr[node + 1];

    float2 a0 = {0.f, 0.f}, a1 = {0.f, 0.f}, a2 = {0.f, 0.f}, a3 = {0.f, 0.f};
    for (int base = beg; base < end; base += 64) {
        int cnt = min(64, end - base);
        int myidx = (lane < cnt) ? srclist[base + lane] : 0;
        int j = 0;
        for (; j + 4 <= cnt; j += 4) {
            int s0 = __shfl(myidx, j);
            int s1 = __shfl(myidx, j + 1);
            int s2 = __shfl(myidx, j + 2);
            int s3 = __shfl(myidx, j + 3);
            uint w0 = Xb[(size_t)s0 * 64 + lane];
            uint w1 = Xb[(size_t)s1 * 64 + lane];
            uint w2 = Xb[(size_t)s2 * 64 + lane];
            uint w3 = Xb[(size_t)s3 * 64 + lane];
            a0.x += bflo(w0); a0.y += bfhi(w0);
            a1.x += bflo(w1); a1.y += bfhi(w1);
            a2.x += bflo(w2); a2.y += bfhi(w2);
            a3.x += bflo(w3); a3.y += bfhi(w3);
        }
        for (; j < cnt; ++j) {
            int s0 = __shfl(myidx, j);
            uint w0 = Xb[(size_t)s0 * 64 + lane];
            a0.x += bflo(w0); a0.y += bfhi(w0);
        }
    }
    float2 acc;
    acc.x = (a0.x + a1.x) + (a2.x + a3.x);
    acc.y = (a0.y + a1.y) + (a2.y + a3.y);
    st2(&AGG[(size_t)node * NF + lane * 2], acc);
}

// ---------------- fused dual GEMM: C = relu(A@Wa + B@Wb + bias) ----------------
// A fp32 [N][128]; B fp32 or bf16 table; out fp32 or bf16 table.
template<int B_BF16, int OUT_BF16>
__global__ __launch_bounds__(256) void dualgemm_k(
    const float* __restrict__ A, const float* __restrict__ Wa,
    const float* __restrict__ Bf, const uint* __restrict__ Bb,
    const float* __restrict__ Wb,
    const float* __restrict__ bias,
    float* __restrict__ Cf, uint* __restrict__ Cb16, int N)
{
    const int lane = threadIdx.x & 63;
    const int wid  = threadIdx.x >> 6;
    const int rowBase = (blockIdx.x * 4 + wid) * 4;
    if (rowBase >= N) return;

    float2 xa[4], xb[4];
#pragma unroll
    for (int r = 0; r < 4; ++r) {
        xa[r] = ld2(&A[(size_t)(rowBase + r) * NF + lane * 2]);
        if (B_BF16) {
            uint w = Bb[(size_t)(rowBase + r) * 64 + lane];
            xb[r].x = bflo(w); xb[r].y = bfhi(w);
        } else {
            xb[r] = ld2(&Bf[(size_t)(rowBase + r) * NF + lane * 2]);
        }
    }
    float2 acc[4];
#pragma unroll
    for (int r = 0; r < 4; ++r) { acc[r].x = 0.f; acc[r].y = 0.f; }

#pragma unroll 4
    for (int kk = 0; kk < 64; ++kk) {
        float2 wa0 = ld2(&Wa[(2*kk)     * NF + lane*2]);
        float2 wa1 = ld2(&Wa[(2*kk + 1) * NF + lane*2]);
        float2 wb0 = ld2(&Wb[(2*kk)     * NF + lane*2]);
        float2 wb1 = ld2(&Wb[(2*kk + 1) * NF + lane*2]);
#pragma unroll
        for (int r = 0; r < 4; ++r) {
            float a0 = __shfl(xa[r].x, kk);
            float a1 = __shfl(xa[r].y, kk);
            float b0 = __shfl(xb[r].x, kk);
            float b1 = __shfl(xb[r].y, kk);
            acc[r].x = fmaf(a0, wa0.x, fmaf(a1, wa1.x, fmaf(b0, wb0.x, fmaf(b1, wb1.x, acc[r].x))));
            acc[r].y = fmaf(a0, wa0.y, fmaf(a1, wa1.y, fmaf(b0, wb0.y, fmaf(b1, wb1.y, acc[r].y))));
        }
    }

#pragma unroll
    for (int r = 0; r < 4; ++r) {
        float2 b = ld2(&bias[lane*2]);
        float2 v = acc[r];
        v.x = fmaxf(v.x + b.x, 0.f);
        v.y = fmaxf(v.y + b.y, 0.f);
        if (OUT_BF16) Cb16[(size_t)(rowBase + r) * 64 + lane] = pack2bf(v.x, v.y);
        else          st2(&Cf[(size_t)(rowBase + r) * NF + lane*2], v);
    }
}

// ---------------- head GEMM: PRb row = interleaved [P-pair | R-pair] per lane,
//                             QSb row = interleaved [Q-pair | S-pair] per lane --------
__global__ __launch_bounds__(256) void headgemm_k(
    const float* __restrict__ H,
    const float* __restrict__ Wm1, const float* __restrict__ bm1,
    const float* __restrict__ Wv1, const float* __restrict__ bv1,
    uint* __restrict__ PRb, uint* __restrict__ QSb, int N)
{
    const int lane = threadIdx.x & 63;
    const int wid  = threadIdx.x >> 6;
    const int rowBase = (blockIdx.x * 4 + wid) * 4;
    if (rowBase >= N) return;

    float2 x2[4];
#pragma unroll
    for (int r = 0; r < 4; ++r)
        x2[r] = ld2(&H[(size_t)(rowBase + r) * NF + lane * 2]);

    float2 ap[4], aq[4], ar[4], as_[4];
#pragma unroll
    for (int r = 0; r < 4; ++r) {
        ap[r] = make_float2(0.f, 0.f); aq[r] = make_float2(0.f, 0.f);
        ar[r] = make_float2(0.f, 0.f); as_[r] = make_float2(0.f, 0.f);
    }

    const float* Wm1b = Wm1 + (size_t)NF * NF;
    const float* Wv1b = Wv1 + (size_t)NF * NF;

#pragma unroll 2
    for (int kk = 0; kk < 64; ++kk) {
        float2 wp0 = ld2(&Wm1 [(2*kk)   * NF + lane*2]);
        float2 wp1 = ld2(&Wm1 [(2*kk+1) * NF + lane*2]);
        float2 wq0 = ld2(&Wm1b[(2*kk)   * NF + lane*2]);
        float2 wq1 = ld2(&Wm1b[(2*kk+1) * NF + lane*2]);
        float2 wr0 = ld2(&Wv1 [(2*kk)   * NF + lane*2]);
        float2 wr1 = ld2(&Wv1 [(2*kk+1) * NF + lane*2]);
        float2 ws0 = ld2(&Wv1b[(2*kk)   * NF + lane*2]);
        float2 ws1 = ld2(&Wv1b[(2*kk+1) * NF + lane*2]);
#pragma unroll
        for (int r = 0; r < 4; ++r) {
            float h0 = __shfl(x2[r].x, kk);
            float h1 = __shfl(x2[r].y, kk);
            ap[r].x = fmaf(h0, wp0.x, fmaf(h1, wp1.x, ap[r].x));
            ap[r].y = fmaf(h0, wp0.y, fmaf(h1, wp1.y, ap[r].y));
            aq[r].x = fmaf(h0, wq0.x, fmaf(h1, wq1.x, aq[r].x));
            aq[r].y = fmaf(h0, wq0.y, fmaf(h1, wq1.y, aq[r].y));
            ar[r].x = fmaf(h0, wr0.x, fmaf(h1, wr1.x, ar[r].x));
            ar[r].y = fmaf(h0, wr0.y, fmaf(h1, wr1.y, ar[r].y));
            as_[r].x = fmaf(h0, ws0.x, fmaf(h1, ws1.x, as_[r].x));
            as_[r].y = fmaf(h0, ws0.y, fmaf(h1, ws1.y, as_[r].y));
        }
    }

    float2 bm = ld2(&bm1[lane*2]);
    float2 bv = ld2(&bv1[lane*2]);
#pragma unroll
    for (int r = 0; r < 4; ++r) {
        size_t row = (size_t)(rowBase + r) * 128;   // 128 dwords per row
        float2 p  = ap[r]; p.x += bm.x; p.y += bm.y;
        float2 rr = ar[r]; rr.x += bv.x; rr.y += bv.y;
        uint2 prw, qsw;
        prw.x = pack2bf(p.x, p.y);
        prw.y = pack2bf(rr.x, rr.y);
        qsw.x = pack2bf(aq[r].x, aq[r].y);
        qsw.y = pack2bf(as_[r].x, as_[r].y);
        *reinterpret_cast<uint2*>(&PRb[row + lane * 2]) = prw;
        *reinterpret_cast<uint2*>(&QSb[row + lane * 2]) = qsw;
    }
}

// ---------------- dst-grouped edge epilogue ----------------
// one wave per dst node: QS[dst] loaded once, iterate in-edges gathering PR[src].
__global__ __launch_bounds__(256) void edge_head2_k(
    const uint* __restrict__ PRb, const uint* __restrict__ QSb,
    const int* __restrict__ rowptr,
    const int* __restrict__ srclist, const int* __restrict__ eidlist,
    const float* __restrict__ Wm2, const float* __restrict__ Wv2,
    const float* __restrict__ bm2, const float* __restrict__ bv2,
    float* __restrict__ mean_out, float* __restrict__ var_out, int N)
{
    int gid  = blockIdx.x * 256 + threadIdx.x;
    int node = gid >> 6;
    int lane = gid & 63;
    if (node >= N) return;
    int beg = rowptr[node];
    int end = rowptr[node + 1];
    if (beg == end) return;

    uint2 qsw = *reinterpret_cast<const uint2*>(&QSb[(size_t)node * 128 + lane * 2]);
    float qx = bflo(qsw.x), qy = bfhi(qsw.x);
    float tx = bflo(qsw.y), ty = bfhi(qsw.y);

    float2 wm = ld2(&Wm2[lane*2]);
    float2 wv = ld2(&Wv2[lane*2]);
    float bm2v = bm2[0];
    float bv2v = bv2[0];

    for (int base = beg; base < end; base += 64) {
        int cnt = min(64, end - base);
        int mysrc = (lane < cnt) ? srclist[base + lane] : 0;
        int myeid = (lane < cnt) ? eidlist[base + lane] : 0;
        for (int j = 0; j < cnt; ++j) {
            int s   = __shfl(mysrc, j);
            int eid = __shfl(myeid, j);
            uint2 prw = *reinterpret_cast<const uint2*>(&PRb[(size_t)s * 128 + lane * 2]);
            float px = bflo(prw.x), py = bfhi(prw.x);
            float rx = bflo(prw.y), ry = bfhi(prw.y);

            float ux = fmaxf(px + qx, 0.f);
            float uy = fmaxf(py + qy, 0.f);
            float vx = fmaxf(rx + tx, 0.f);
            float vy = fmaxf(ry + ty, 0.f);

            float pm = fmaf(ux, wm.x, uy * wm.y);
            float pv = fmaf(vx, wv.x, vy * wv.y);
#pragma unroll
            for (int off = 32; off > 0; off >>= 1) {
                pm += __shfl_xor(pm, off);
                pv += __shfl_xor(pv, off);
            }
            if (lane == 0) {
                mean_out[eid] = pm + bm2v;
                var_out[eid]  = expf(0.5f * (pv + bv2v));
            }
        }
    }
}

extern "C" void kernel_launch(void* const* d_in, const int* in_sizes, int n_in,
                              void* d_out, int out_size, void* d_ws, size_t ws_size,
                              hipStream_t stream)
{
    const float* x       = (const float*)d_in[0];
    const int*   ei      = (const int*)d_in[1];
    const float* W1_rel  = (const float*)d_in[2];
    const float* b1      = (const float*)d_in[3];
    const float* W1_root = (const float*)d_in[4];
    const float* W2_rel  = (const float*)d_in[5];
    const float* b2      = (const float*)d_in[6];
    const float* W2_root = (const float*)d_in[7];
    const float* Wm1     = (const float*)d_in[8];
    const float* bm1     = (const float*)d_in[9];
    const float* Wm2     = (const float*)d_in[10];
    const float* bm2     = (const float*)d_in[11];
    const float* Wv1     = (const float*)d_in[12];
    const float* bv1     = (const float*)d_in[13];
    const float* Wv2     = (const float*)d_in[14];
    const float* bv2     = (const float*)d_in[15];

    const int N = in_sizes[0] / NF;   // 50000
    const int E = in_sizes[1] / 2;    // 800000

    const size_t SZ32 = (size_t)N * NF * 4;       // 25.6 MB fp32 node table
    const size_t SZ16 = (size_t)N * NF * 2;       // 12.8 MB bf16 node table

    char* base = (char*)d_ws;
    // region0 [0, SZ32): x_b (lo half) + h1b (hi half); later PRb (full)
    // region1 [SZ32, 2*SZ32): AGG fp32; later QSb
    // region2 [2*SZ32, 3*SZ32): h2 fp32
    uint*  x_b  = (uint*)(base);
    uint*  h1b  = (uint*)(base + SZ16);
    uint*  PRb  = (uint*)(base);
    float* AGG  = (float*)(base + SZ32);
    uint*  QSb  = (uint*)(base + SZ32);
    float* h2   = (float*)(base + 2 * SZ32);

    char* csr = base + 3 * SZ32;
    int* deg     = (int*)(csr);
    int* rowptr  = (int*)(csr + (size_t)(N + 64) * 4);
    int* cursor  = (int*)(csr + (size_t)(N + 64) * 8);
    int* srclist = (int*)(csr + (size_t)(N + 64) * 12);
    int* eidlist = srclist + E;

    float* out_mean = (float*)d_out;
    float* out_var  = out_mean + E;

    dim3 blk(256);
    dim3 eGrid((E + 255) / 256);                          // 3125
    dim3 gemmGrid((N + 15) / 16);                         // 3125
    dim3 nodeGrid((unsigned)(((size_t)N * 64 + 255) / 256)); // 12500
    dim3 castGrid((unsigned)(((size_t)N * 64 + 255) / 256)); // pairs = N*64

    // ---- cast x to bf16 table (aggregation source only)
    hipLaunchKernelGGL(cast_bf16_k, castGrid, blk, 0, stream, x, x_b, N * 64);

    // ---- CSR build (srclist + eidlist, grouped by dst)
    hipMemsetAsync(deg, 0, (size_t)N * 4, stream);
    hipLaunchKernelGGL(count_k, eGrid, blk, 0, stream, ei, deg, E);
    hipLaunchKernelGGL(scan_k, dim3(1), dim3(1024), 0, stream, deg, rowptr, cursor, N);
    hipLaunchKernelGGL(fill_k, eGrid, blk, 0, stream, ei, cursor, srclist, eidlist, E);

    // ---- conv1: h1 = relu(segsum(x)@W1_rel + x@W1_root + b1)  (h1 stored bf16)
    hipLaunchKernelGGL(agg_bf16_k, nodeGrid, blk, 0, stream, x_b, rowptr, srclist, AGG, N);
    hipLaunchKernelGGL((dualgemm_k<0,1>), gemmGrid, blk, 0, stream,
                       AGG, W1_rel, x, (const uint*)nullptr, W1_root, b1,
                       (float*)nullptr, h1b, N);

    // ---- conv2: h2 = relu(segsum(h1)@W2_rel + h1@W2_root + b2)  (h2 fp32)
    hipLaunchKernelGGL(agg_bf16_k, nodeGrid, blk, 0, stream, h1b, rowptr, srclist, AGG, N);
    hipLaunchKernelGGL((dualgemm_k<1,0>), gemmGrid, blk, 0, stream,
                       AGG, W2_rel, (const float*)nullptr, h1b, W2_root, b2,
                       h2, (uint*)nullptr, N);

    // ---- node-level head precompute: PRb (over x_b+h1b), QSb (over AGG)
    hipLaunchKernelGGL(headgemm_k, gemmGrid, blk, 0, stream,
                       h2, Wm1, bm1, Wv1, bv1, PRb, QSb, N);

    // ---- dst-grouped per-edge epilogue
    hipLaunchKernelGGL(edge_head2_k, nodeGrid, blk, 0, stream,
                       PRb, QSb, rowptr, srclist, eidlist,
                       Wm2, Wv2, bm2, bv2, out_mean, out_var, N);
}

// Round 7
// 634.722 us; speedup vs baseline: 3.5074x; 1.5445x over previous
//
#include <hip/hip_runtime.h>
#include <cstdint>

#define NF 128

typedef unsigned int uint;
typedef short bf16x8 __attribute__((ext_vector_type(8)));
typedef float f32x4  __attribute__((ext_vector_type(4)));

__device__ __forceinline__ float2 ld2(const float* p) {
    return *reinterpret_cast<const float2*>(p);
}
__device__ __forceinline__ void st2(float* p, float2 v) {
    *reinterpret_cast<float2*>(p) = v;
}
// bf16 pair packed in a uint: elem0 = bits[15:0], elem1 = bits[31:16]
__device__ __forceinline__ float bflo(uint u) { return __uint_as_float(u << 16); }
__device__ __forceinline__ float bfhi(uint u) { return __uint_as_float(u & 0xffff0000u); }
__device__ __forceinline__ uint f2bf_rne(float f) {
    uint u = __float_as_uint(f);
    return (u + 0x7fffu + ((u >> 16) & 1u)) >> 16;
}
__device__ __forceinline__ uint pack2bf(float a, float b) {
    return f2bf_rne(a) | (f2bf_rne(b) << 16);
}

// load an 8-bf16 k-slice fragment from a packed table [*][64] uints.
// identical addressing for A(weight) and B(activation) operands -> any k-permutation
// assumption cancels inside the MFMA dot product.
__device__ __forceinline__ bf16x8 ldfrag(const uint* __restrict__ tab, int idx, int kb, int g) {
    const uint4 u = *reinterpret_cast<const uint4*>(&tab[(size_t)idx * 64 + kb * 16 + g * 4]);
    union { uint4 u4; bf16x8 b; } c; c.u4 = u; return c.b;
}

// ---------------- fp32 -> bf16 table cast ----------------
__global__ __launch_bounds__(256) void cast_bf16_k(const float* __restrict__ in,
                                                   uint* __restrict__ out, int npairs)
{
    int i = blockIdx.x * 256 + threadIdx.x;
    if (i >= npairs) return;
    float2 v = ld2(&in[(size_t)i * 2]);
    out[i] = pack2bf(v.x, v.y);
}

// ---------------- weight transpose+cast: WT[c][k] = W[k][c], bf16-packed --------
struct W8 {
    const float* src[8];
    uint*        dst[8];
};
__global__ __launch_bounds__(256) void wtpack_k(W8 p)
{
    int m = blockIdx.y;
    const float* s = p.src[m];
    uint* d = p.dst[m];
    int idx = blockIdx.x * 256 + threadIdx.x;     // [0, 8192)
    int c   = idx >> 6;
    int kdw = idx & 63;
    float a = s[(size_t)(2 * kdw)     * NF + c];
    float b = s[(size_t)(2 * kdw + 1) * NF + c];
    d[(size_t)c * 64 + kdw] = pack2bf(a, b);
}

// ---------------- CSR build ----------------
__global__ __launch_bounds__(256) void count_k(const int* __restrict__ ei,
                                               int* __restrict__ deg, int E)
{
    int e = blockIdx.x * 256 + threadIdx.x;
    if (e >= E) return;
    atomicAdd(&deg[ei[E + e]], 1);
}

__global__ __launch_bounds__(1024) void scan_k(const int* __restrict__ deg,
                                               int* __restrict__ rowptr,
                                               int* __restrict__ cursor, int N)
{
    __shared__ int ssum[1024];
    int tid = threadIdx.x;
    int chunk = (N + 1023) / 1024;
    int beg = tid * chunk;
    int end = min(beg + chunk, N);
    int s = 0;
    for (int i = beg; i < end; ++i) s += deg[i];
    ssum[tid] = s;
    __syncthreads();
    for (int off = 1; off < 1024; off <<= 1) {
        int v = (tid >= off) ? ssum[tid - off] : 0;
        __syncthreads();
        ssum[tid] += v;
        __syncthreads();
    }
    int run = (tid == 0) ? 0 : ssum[tid - 1];
    for (int i = beg; i < end; ++i) {
        rowptr[i] = run;
        cursor[i] = run;
        run += deg[i];
    }
    if (end == N) rowptr[N] = run;
}

__global__ __launch_bounds__(256) void fill_k(const int* __restrict__ ei,
                                              int* __restrict__ cursor,
                                              int* __restrict__ srclist,
                                              int* __restrict__ eidlist, int E)
{
    int e = blockIdx.x * 256 + threadIdx.x;
    if (e >= E) return;
    int s = ei[e];
    int d = ei[E + e];
    int pos = atomicAdd(&cursor[d], 1);
    srclist[pos] = s;
    eidlist[pos] = e;
}

// ---------------- aggregation: AGGb[i] = bf16( sum_{j in in(i)} X[j] ) ------
__global__ __launch_bounds__(256) void agg_bf16_k(const uint* __restrict__ Xb,
                                                  const int* __restrict__ rowptr,
                                                  const int* __restrict__ srclist,
                                                  uint* __restrict__ AGGb, int N)
{
    int gid  = blockIdx.x * 256 + threadIdx.x;
    int node = gid >> 6;
    int lane = gid & 63;
    if (node >= N) return;
    int beg = rowptr[node];
    int end = rowptr[node + 1];

    float2 a0 = {0.f, 0.f}, a1 = {0.f, 0.f}, a2 = {0.f, 0.f}, a3 = {0.f, 0.f};
    for (int base = beg; base < end; base += 64) {
        int cnt = min(64, end - base);
        int myidx = (lane < cnt) ? srclist[base + lane] : 0;
        int j = 0;
        for (; j + 4 <= cnt; j += 4) {
            int s0 = __shfl(myidx, j);
            int s1 = __shfl(myidx, j + 1);
            int s2 = __shfl(myidx, j + 2);
            int s3 = __shfl(myidx, j + 3);
            uint w0 = Xb[(size_t)s0 * 64 + lane];
            uint w1 = Xb[(size_t)s1 * 64 + lane];
            uint w2 = Xb[(size_t)s2 * 64 + lane];
            uint w3 = Xb[(size_t)s3 * 64 + lane];
            a0.x += bflo(w0); a0.y += bfhi(w0);
            a1.x += bflo(w1); a1.y += bfhi(w1);
            a2.x += bflo(w2); a2.y += bfhi(w2);
            a3.x += bflo(w3); a3.y += bfhi(w3);
        }
        for (; j < cnt; ++j) {
            int s0 = __shfl(myidx, j);
            uint w0 = Xb[(size_t)s0 * 64 + lane];
            a0.x += bflo(w0); a0.y += bfhi(w0);
        }
    }
    float sx = (a0.x + a1.x) + (a2.x + a3.x);
    float sy = (a0.y + a1.y) + (a2.y + a3.y);
    AGGb[(size_t)node * 64 + lane] = pack2bf(sx, sy);
}

// ---------------- MFMA dual GEMM: C = bf16(relu(Aa@Wa + Ab@Wb + bias)) --------
// A-operand = weight col-tile (WT tables), B-operand = activation rows.
// D mapping (HW-verified): n = lane&15 -> activation row; m = (lane>>4)*4+reg -> col.
__global__ __launch_bounds__(256) void dualgemm_mfma_k(
    const uint* __restrict__ Aa, const uint* __restrict__ WaT,
    const uint* __restrict__ Ab, const uint* __restrict__ WbT,
    const float* __restrict__ bias, uint* __restrict__ C, int Nrows)
{
    const int lane = threadIdx.x & 63;
    const int wid  = threadIdx.x >> 6;
    const int g    = lane >> 4;
    const int r15  = lane & 15;
    const int rowBase = blockIdx.x * 64 + wid * 16;
    if (rowBase >= Nrows) return;
    const int arow = rowBase + r15;

    bf16x8 ba[4], bb[4];
#pragma unroll
    for (int kb = 0; kb < 4; ++kb) {
        ba[kb] = ldfrag(Aa, arow, kb, g);
        bb[kb] = ldfrag(Ab, arow, kb, g);
    }

#pragma unroll
    for (int ct = 0; ct < 8; ++ct) {
        const int wcol = ct * 16 + r15;
        f32x4 acc = {0.f, 0.f, 0.f, 0.f};
#pragma unroll
        for (int kb = 0; kb < 4; ++kb)
            acc = __builtin_amdgcn_mfma_f32_16x16x32_bf16(ldfrag(WaT, wcol, kb, g), ba[kb], acc, 0, 0, 0);
#pragma unroll
        for (int kb = 0; kb < 4; ++kb)
            acc = __builtin_amdgcn_mfma_f32_16x16x32_bf16(ldfrag(WbT, wcol, kb, g), bb[kb], acc, 0, 0, 0);

        const int colBase = ct * 16 + g * 4;
        float4 bs = *reinterpret_cast<const float4*>(&bias[colBase]);
        float v0 = fmaxf(acc[0] + bs.x, 0.f);
        float v1 = fmaxf(acc[1] + bs.y, 0.f);
        float v2 = fmaxf(acc[2] + bs.z, 0.f);
        float v3 = fmaxf(acc[3] + bs.w, 0.f);
        uint2 pk;
        pk.x = pack2bf(v0, v1);
        pk.y = pack2bf(v2, v3);
        *reinterpret_cast<uint2*>(&C[(size_t)arow * 64 + ct * 8 + g * 2]) = pk;
    }
}

// ---------------- MFMA head GEMM: PRb/QSb interleaved bf16 tables --------------
__global__ __launch_bounds__(256) void headgemm_mfma_k(
    const uint* __restrict__ Hb,
    const uint* __restrict__ WPt, const uint* __restrict__ WQt,
    const uint* __restrict__ WRt, const uint* __restrict__ WSt,
    const float* __restrict__ bm1, const float* __restrict__ bv1,
    uint* __restrict__ PRb, uint* __restrict__ QSb, int Nrows)
{
    const int lane = threadIdx.x & 63;
    const int wid  = threadIdx.x >> 6;
    const int g    = lane >> 4;
    const int r15  = lane & 15;
    const int rowBase = blockIdx.x * 64 + wid * 16;
    if (rowBase >= Nrows) return;
    const int arow = rowBase + r15;

    bf16x8 hb[4];
#pragma unroll
    for (int kb = 0; kb < 4; ++kb) hb[kb] = ldfrag(Hb, arow, kb, g);

#pragma unroll
    for (int ct = 0; ct < 8; ++ct) {
        const int wcol = ct * 16 + r15;
        f32x4 aP = {0.f,0.f,0.f,0.f}, aQ = {0.f,0.f,0.f,0.f};
        f32x4 aR = {0.f,0.f,0.f,0.f}, aS = {0.f,0.f,0.f,0.f};
#pragma unroll
        for (int kb = 0; kb < 4; ++kb) {
            aP = __builtin_amdgcn_mfma_f32_16x16x32_bf16(ldfrag(WPt, wcol, kb, g), hb[kb], aP, 0, 0, 0);
            aQ = __builtin_amdgcn_mfma_f32_16x16x32_bf16(ldfrag(WQt, wcol, kb, g), hb[kb], aQ, 0, 0, 0);
            aR = __builtin_amdgcn_mfma_f32_16x16x32_bf16(ldfrag(WRt, wcol, kb, g), hb[kb], aR, 0, 0, 0);
            aS = __builtin_amdgcn_mfma_f32_16x16x32_bf16(ldfrag(WSt, wcol, kb, g), hb[kb], aS, 0, 0, 0);
        }
        const int colBase = ct * 16 + g * 4;
        float4 bmv = *reinterpret_cast<const float4*>(&bm1[colBase]);
        float4 bvv = *reinterpret_cast<const float4*>(&bv1[colBase]);
        float p0 = aP[0] + bmv.x, p1 = aP[1] + bmv.y, p2 = aP[2] + bmv.z, p3 = aP[3] + bmv.w;
        float r0 = aR[0] + bvv.x, r1 = aR[1] + bvv.y, r2 = aR[2] + bvv.z, r3 = aR[3] + bvv.w;
        uint4 pr, qs;
        pr.x = pack2bf(p0, p1);     pr.y = pack2bf(r0, r1);
        pr.z = pack2bf(p2, p3);     pr.w = pack2bf(r2, r3);
        qs.x = pack2bf(aQ[0], aQ[1]); qs.y = pack2bf(aS[0], aS[1]);
        qs.z = pack2bf(aQ[2], aQ[3]); qs.w = pack2bf(aS[2], aS[3]);
        *reinterpret_cast<uint4*>(&PRb[(size_t)arow * 128 + ct * 16 + g * 4]) = pr;
        *reinterpret_cast<uint4*>(&QSb[(size_t)arow * 128 + ct * 16 + g * 4]) = qs;
    }
}

// ---------------- dst-grouped edge epilogue ----------------
__global__ __launch_bounds__(256) void edge_head2_k(
    const uint* __restrict__ PRb, const uint* __restrict__ QSb,
    const int* __restrict__ rowptr,
    const int* __restrict__ srclist, const int* __restrict__ eidlist,
    const float* __restrict__ Wm2, const float* __restrict__ Wv2,
    const float* __restrict__ bm2, const float* __restrict__ bv2,
    float* __restrict__ mean_out, float* __restrict__ var_out, int N)
{
    int gid  = blockIdx.x * 256 + threadIdx.x;
    int node = gid >> 6;
    int lane = gid & 63;
    if (node >= N) return;
    int beg = rowptr[node];
    int end = rowptr[node + 1];
    if (beg == end) return;

    uint2 qsw = *reinterpret_cast<const uint2*>(&QSb[(size_t)node * 128 + lane * 2]);
    float qx = bflo(qsw.x), qy = bfhi(qsw.x);
    float tx = bflo(qsw.y), ty = bfhi(qsw.y);

    float2 wm = ld2(&Wm2[lane*2]);
    float2 wv = ld2(&Wv2[lane*2]);
    float bm2v = bm2[0];
    float bv2v = bv2[0];

    for (int base = beg; base < end; base += 64) {
        int cnt = min(64, end - base);
        int mysrc = (lane < cnt) ? srclist[base + lane] : 0;
        int myeid = (lane < cnt) ? eidlist[base + lane] : 0;
        for (int j = 0; j < cnt; ++j) {
            int s   = __shfl(mysrc, j);
            int eid = __shfl(myeid, j);
            uint2 prw = *reinterpret_cast<const uint2*>(&PRb[(size_t)s * 128 + lane * 2]);
            float px = bflo(prw.x), py = bfhi(prw.x);
            float rx = bflo(prw.y), ry = bfhi(prw.y);

            float ux = fmaxf(px + qx, 0.f);
            float uy = fmaxf(py + qy, 0.f);
            float vx = fmaxf(rx + tx, 0.f);
            float vy = fmaxf(ry + ty, 0.f);

            float pm = fmaf(ux, wm.x, uy * wm.y);
            float pv = fmaf(vx, wv.x, vy * wv.y);
#pragma unroll
            for (int off = 32; off > 0; off >>= 1) {
                pm += __shfl_xor(pm, off);
                pv += __shfl_xor(pv, off);
            }
            if (lane == 0) {
                mean_out[eid] = pm + bm2v;
                var_out[eid]  = expf(0.5f * (pv + bv2v));
            }
        }
    }
}

extern "C" void kernel_launch(void* const* d_in, const int* in_sizes, int n_in,
                              void* d_out, int out_size, void* d_ws, size_t ws_size,
                              hipStream_t stream)
{
    const float* x       = (const float*)d_in[0];
    const int*   ei      = (const int*)d_in[1];
    const float* W1_rel  = (const float*)d_in[2];
    const float* b1      = (const float*)d_in[3];
    const float* W1_root = (const float*)d_in[4];
    const float* W2_rel  = (const float*)d_in[5];
    const float* b2      = (const float*)d_in[6];
    const float* W2_root = (const float*)d_in[7];
    const float* Wm1     = (const float*)d_in[8];
    const float* bm1     = (const float*)d_in[9];
    const float* Wm2     = (const float*)d_in[10];
    const float* bm2     = (const float*)d_in[11];
    const float* Wv1     = (const float*)d_in[12];
    const float* bv1     = (const float*)d_in[13];
    const float* Wv2     = (const float*)d_in[14];
    const float* bv2     = (const float*)d_in[15];

    const int N = in_sizes[0] / NF;   // 50000
    const int E = in_sizes[1] / 2;    // 800000

    const size_t SZ16 = (size_t)N * NF * 2;       // 12.8 MB bf16 node table

    char* base = (char*)d_ws;
    // [0,S): x_b, later h2b | [S,2S): h1b | [2S,3S): AGGb | PRb = [S,3S) | QSb = [3S,5S)
    uint* x_b  = (uint*)(base);
    uint* h2b  = (uint*)(base);
    uint* h1b  = (uint*)(base + SZ16);
    uint* AGGb = (uint*)(base + 2 * SZ16);
    uint* PRb  = (uint*)(base + SZ16);
    uint* QSb  = (uint*)(base + 3 * SZ16);

    char* wts = base + 5 * SZ16;
    uint* wt[8];
    for (int i = 0; i < 8; ++i) wt[i] = (uint*)(wts + (size_t)i * 32768);

    char* csr = wts + 8 * 32768;
    int* deg     = (int*)(csr);
    int* rowptr  = (int*)(csr + (size_t)(N + 64) * 4);
    int* cursor  = (int*)(csr + (size_t)(N + 64) * 8);
    int* srclist = (int*)(csr + (size_t)(N + 64) * 12);
    int* eidlist = srclist + E;

    float* out_mean = (float*)d_out;
    float* out_var  = out_mean + E;

    dim3 blk(256);
    dim3 eGrid((E + 255) / 256);                             // 3125
    dim3 mfmaGrid((N + 63) / 64);                            // 782
    dim3 nodeGrid((unsigned)(((size_t)N * 64 + 255) / 256)); // 12500

    // ---- cast x to bf16 table
    hipLaunchKernelGGL(cast_bf16_k, nodeGrid, blk, 0, stream, x, x_b, N * 64);

    // ---- pack all weights: WT[c][k] bf16
    W8 wp;
    wp.src[0] = W1_rel;            wp.dst[0] = wt[0];
    wp.src[1] = W1_root;           wp.dst[1] = wt[1];
    wp.src[2] = W2_rel;            wp.dst[2] = wt[2];
    wp.src[3] = W2_root;           wp.dst[3] = wt[3];
    wp.src[4] = Wm1;               wp.dst[4] = wt[4];   // P (src half)
    wp.src[5] = Wm1 + NF * NF;     wp.dst[5] = wt[5];   // Q (dst half)
    wp.src[6] = Wv1;               wp.dst[6] = wt[6];   // R
    wp.src[7] = Wv1 + NF * NF;     wp.dst[7] = wt[7];   // S
    hipLaunchKernelGGL(wtpack_k, dim3(32, 8), blk, 0, stream, wp);

    // ---- CSR build
    hipMemsetAsync(deg, 0, (size_t)N * 4, stream);
    hipLaunchKernelGGL(count_k, eGrid, blk, 0, stream, ei, deg, E);
    hipLaunchKernelGGL(scan_k, dim3(1), dim3(1024), 0, stream, deg, rowptr, cursor, N);
    hipLaunchKernelGGL(fill_k, eGrid, blk, 0, stream, ei, cursor, srclist, eidlist, E);

    // ---- conv1: h1 = relu(segsum(x)@W1_rel + x@W1_root + b1)
    hipLaunchKernelGGL(agg_bf16_k, nodeGrid, blk, 0, stream, x_b, rowptr, srclist, AGGb, N);
    hipLaunchKernelGGL(dualgemm_mfma_k, mfmaGrid, blk, 0, stream,
                       AGGb, wt[0], x_b, wt[1], b1, h1b, N);

    // ---- conv2: h2 = relu(segsum(h1)@W2_rel + h1@W2_root + b2)  (h2b over x_b)
    hipLaunchKernelGGL(agg_bf16_k, nodeGrid, blk, 0, stream, h1b, rowptr, srclist, AGGb, N);
    hipLaunchKernelGGL(dualgemm_mfma_k, mfmaGrid, blk, 0, stream,
                       AGGb, wt[2], h1b, wt[3], b2, h2b, N);

    // ---- head precompute (PRb over h1b+AGGb; both dead now)
    hipLaunchKernelGGL(headgemm_mfma_k, mfmaGrid, blk, 0, stream,
                       h2b, wt[4], wt[5], wt[6], wt[7], bm1, bv1, PRb, QSb, N);

    // ---- dst-grouped per-edge epilogue
    hipLaunchKernelGGL(edge_head2_k, nodeGrid, blk, 0, stream,
                       PRb, QSb, rowptr, srclist, eidlist,
                       Wm2, Wv2, bm2, bv2, out_mean, out_var, N);
}

// Round 8
// 604.334 us; speedup vs baseline: 3.6837x; 1.0503x over previous
//
#include <hip/hip_runtime.h>
#include <cstdint>

#define NF 128

typedef unsigned int uint;
typedef short bf16x8 __attribute__((ext_vector_type(8)));
typedef float f32x4  __attribute__((ext_vector_type(4)));

__device__ __forceinline__ float2 ld2(const float* p) {
    return *reinterpret_cast<const float2*>(p);
}
// bf16 pair packed in a uint: elem0 = bits[15:0], elem1 = bits[31:16]
__device__ __forceinline__ float bflo(uint u) { return __uint_as_float(u << 16); }
__device__ __forceinline__ float bfhi(uint u) { return __uint_as_float(u & 0xffff0000u); }
__device__ __forceinline__ uint f2bf_rne(float f) {
    uint u = __float_as_uint(f);
    return (u + 0x7fffu + ((u >> 16) & 1u)) >> 16;
}
__device__ __forceinline__ uint pack2bf(float a, float b) {
    return f2bf_rne(a) | (f2bf_rne(b) << 16);
}

__device__ __forceinline__ bf16x8 ldfrag(const uint* __restrict__ tab, int idx, int kb, int g) {
    const uint4 u = *reinterpret_cast<const uint4*>(&tab[(size_t)idx * 64 + kb * 16 + g * 4]);
    union { uint4 u4; bf16x8 b; } c; c.u4 = u; return c.b;
}

// ---------------- fp32 -> bf16 table cast ----------------
__global__ __launch_bounds__(256) void cast_bf16_k(const float* __restrict__ in,
                                                   uint* __restrict__ out, int npairs)
{
    int i = blockIdx.x * 256 + threadIdx.x;
    if (i >= npairs) return;
    float2 v = ld2(&in[(size_t)i * 2]);
    out[i] = pack2bf(v.x, v.y);
}

// ---------------- weight transpose+cast: WT[c][k] = W[k][c], bf16-packed --------
struct W8 {
    const float* src[8];
    uint*        dst[8];
};
__global__ __launch_bounds__(256) void wtpack_k(W8 p)
{
    int m = blockIdx.y;
    const float* s = p.src[m];
    uint* d = p.dst[m];
    int idx = blockIdx.x * 256 + threadIdx.x;     // [0, 8192)
    int c   = idx >> 6;
    int kdw = idx & 63;
    float a = s[(size_t)(2 * kdw)     * NF + c];
    float b = s[(size_t)(2 * kdw + 1) * NF + c];
    d[(size_t)c * 64 + kdw] = pack2bf(a, b);
}

// ---------------- CSR build ----------------
__global__ __launch_bounds__(256) void count_k(const int* __restrict__ ei,
                                               int* __restrict__ deg, int E)
{
    int e = blockIdx.x * 256 + threadIdx.x;
    if (e >= E) return;
    atomicAdd(&deg[ei[E + e]], 1);
}

__global__ __launch_bounds__(1024) void scan_k(const int* __restrict__ deg,
                                               int* __restrict__ rowptr,
                                               int* __restrict__ cursor, int N)
{
    __shared__ int ssum[1024];
    int tid = threadIdx.x;
    int chunk = (N + 1023) / 1024;
    int beg = tid * chunk;
    int end = min(beg + chunk, N);
    int s = 0;
    for (int i = beg; i < end; ++i) s += deg[i];
    ssum[tid] = s;
    __syncthreads();
    for (int off = 1; off < 1024; off <<= 1) {
        int v = (tid >= off) ? ssum[tid - off] : 0;
        __syncthreads();
        ssum[tid] += v;
        __syncthreads();
    }
    int run = (tid == 0) ? 0 : ssum[tid - 1];
    for (int i = beg; i < end; ++i) {
        rowptr[i] = run;
        cursor[i] = run;
        run += deg[i];
    }
    if (end == N) rowptr[N] = run;
}

// srclist[pos]=src (scattered), invpos[e]=pos (coalesced)
__global__ __launch_bounds__(256) void fill_k(const int* __restrict__ ei,
                                              int* __restrict__ cursor,
                                              int* __restrict__ srclist,
                                              int* __restrict__ invpos, int E)
{
    int e = blockIdx.x * 256 + threadIdx.x;
    if (e >= E) return;
    int s = ei[e];
    int d = ei[E + e];
    int pos = atomicAdd(&cursor[d], 1);
    srclist[pos] = s;
    invpos[e] = pos;
}

// ---------------- aggregation: 2 nodes per wave, 32 lanes each ----------------
// lane covers dims 4*hlane..4*hlane+3 (uint2 of the 64-dword row).
__global__ __launch_bounds__(256) void agg2_k(const uint* __restrict__ Xb,
                                              const int* __restrict__ rowptr,
                                              const int* __restrict__ srclist,
                                              uint* __restrict__ AGGb, int N)
{
    int gid   = blockIdx.x * 256 + threadIdx.x;
    int wave  = gid >> 6;
    int lane  = gid & 63;
    int half  = lane >> 5;
    int hlane = lane & 31;
    int node  = wave * 2 + half;
    int nc    = min(node, N - 1);
    int beg = rowptr[nc];
    int end = rowptr[nc + 1];
    if (node >= N) { beg = 0; end = 0; }

    float ax = 0.f, ay = 0.f, az = 0.f, aw = 0.f;
    float bx = 0.f, by = 0.f, bz = 0.f, bw = 0.f;
    for (int j = beg; j < end; j += 2) {
        int  ok1 = (j + 1 < end);
        int  s0 = srclist[j];
        int  s1 = ok1 ? srclist[j + 1] : s0;
        uint2 w0 = *reinterpret_cast<const uint2*>(&Xb[(size_t)s0 * 64 + hlane * 2]);
        uint2 w1 = *reinterpret_cast<const uint2*>(&Xb[(size_t)s1 * 64 + hlane * 2]);
        ax += bflo(w0.x); ay += bfhi(w0.x); az += bflo(w0.y); aw += bfhi(w0.y);
        if (ok1) { bx += bflo(w1.x); by += bfhi(w1.x); bz += bflo(w1.y); bw += bfhi(w1.y); }
    }
    if (node < N) {
        uint2 o;
        o.x = pack2bf(ax + bx, ay + by);
        o.y = pack2bf(az + bz, aw + bw);
        *reinterpret_cast<uint2*>(&AGGb[(size_t)node * 64 + hlane * 2]) = o;
    }
}

// ---------------- MFMA dual GEMM: C = bf16(relu(Aa@Wa + Ab@Wb + bias)) --------
__global__ __launch_bounds__(256) void dualgemm_mfma_k(
    const uint* __restrict__ Aa, const uint* __restrict__ WaT,
    const uint* __restrict__ Ab, const uint* __restrict__ WbT,
    const float* __restrict__ bias, uint* __restrict__ C, int Nrows)
{
    const int lane = threadIdx.x & 63;
    const int wid  = threadIdx.x >> 6;
    const int g    = lane >> 4;
    const int r15  = lane & 15;
    const int rowBase = blockIdx.x * 64 + wid * 16;
    if (rowBase >= Nrows) return;
    const int arow = rowBase + r15;

    bf16x8 ba[4], bb[4];
#pragma unroll
    for (int kb = 0; kb < 4; ++kb) {
        ba[kb] = ldfrag(Aa, arow, kb, g);
        bb[kb] = ldfrag(Ab, arow, kb, g);
    }

#pragma unroll
    for (int ct = 0; ct < 8; ++ct) {
        const int wcol = ct * 16 + r15;
        f32x4 acc = {0.f, 0.f, 0.f, 0.f};
#pragma unroll
        for (int kb = 0; kb < 4; ++kb)
            acc = __builtin_amdgcn_mfma_f32_16x16x32_bf16(ldfrag(WaT, wcol, kb, g), ba[kb], acc, 0, 0, 0);
#pragma unroll
        for (int kb = 0; kb < 4; ++kb)
            acc = __builtin_amdgcn_mfma_f32_16x16x32_bf16(ldfrag(WbT, wcol, kb, g), bb[kb], acc, 0, 0, 0);

        const int colBase = ct * 16 + g * 4;
        float4 bs = *reinterpret_cast<const float4*>(&bias[colBase]);
        float v0 = fmaxf(acc[0] + bs.x, 0.f);
        float v1 = fmaxf(acc[1] + bs.y, 0.f);
        float v2 = fmaxf(acc[2] + bs.z, 0.f);
        float v3 = fmaxf(acc[3] + bs.w, 0.f);
        uint2 pk;
        pk.x = pack2bf(v0, v1);
        pk.y = pack2bf(v2, v3);
        *reinterpret_cast<uint2*>(&C[(size_t)arow * 64 + ct * 8 + g * 2]) = pk;
    }
}

// ---------------- MFMA head GEMM: PRb/QSb interleaved bf16 tables --------------
__global__ __launch_bounds__(256) void headgemm_mfma_k(
    const uint* __restrict__ Hb,
    const uint* __restrict__ WPt, const uint* __restrict__ WQt,
    const uint* __restrict__ WRt, const uint* __restrict__ WSt,
    const float* __restrict__ bm1, const float* __restrict__ bv1,
    uint* __restrict__ PRb, uint* __restrict__ QSb, int Nrows)
{
    const int lane = threadIdx.x & 63;
    const int wid  = threadIdx.x >> 6;
    const int g    = lane >> 4;
    const int r15  = lane & 15;
    const int rowBase = blockIdx.x * 64 + wid * 16;
    if (rowBase >= Nrows) return;
    const int arow = rowBase + r15;

    bf16x8 hb[4];
#pragma unroll
    for (int kb = 0; kb < 4; ++kb) hb[kb] = ldfrag(Hb, arow, kb, g);

#pragma unroll
    for (int ct = 0; ct < 8; ++ct) {
        const int wcol = ct * 16 + r15;
        f32x4 aP = {0.f,0.f,0.f,0.f}, aQ = {0.f,0.f,0.f,0.f};
        f32x4 aR = {0.f,0.f,0.f,0.f}, aS = {0.f,0.f,0.f,0.f};
#pragma unroll
        for (int kb = 0; kb < 4; ++kb) {
            aP = __builtin_amdgcn_mfma_f32_16x16x32_bf16(ldfrag(WPt, wcol, kb, g), hb[kb], aP, 0, 0, 0);
            aQ = __builtin_amdgcn_mfma_f32_16x16x32_bf16(ldfrag(WQt, wcol, kb, g), hb[kb], aQ, 0, 0, 0);
            aR = __builtin_amdgcn_mfma_f32_16x16x32_bf16(ldfrag(WRt, wcol, kb, g), hb[kb], aR, 0, 0, 0);
            aS = __builtin_amdgcn_mfma_f32_16x16x32_bf16(ldfrag(WSt, wcol, kb, g), hb[kb], aS, 0, 0, 0);
        }
        const int colBase = ct * 16 + g * 4;
        float4 bmv = *reinterpret_cast<const float4*>(&bm1[colBase]);
        float4 bvv = *reinterpret_cast<const float4*>(&bv1[colBase]);
        float p0 = aP[0] + bmv.x, p1 = aP[1] + bmv.y, p2 = aP[2] + bmv.z, p3 = aP[3] + bmv.w;
        float r0 = aR[0] + bvv.x, r1 = aR[1] + bvv.y, r2 = aR[2] + bvv.z, r3 = aR[3] + bvv.w;
        uint4 pr, qs;
        pr.x = pack2bf(p0, p1);     pr.y = pack2bf(r0, r1);
        pr.z = pack2bf(p2, p3);     pr.w = pack2bf(r2, r3);
        qs.x = pack2bf(aQ[0], aQ[1]); qs.y = pack2bf(aS[0], aS[1]);
        qs.z = pack2bf(aQ[2], aQ[3]); qs.w = pack2bf(aS[2], aS[3]);
        *reinterpret_cast<uint4*>(&PRb[(size_t)arow * 128 + ct * 16 + g * 4]) = pr;
        *reinterpret_cast<uint4*>(&QSb[(size_t)arow * 128 + ct * 16 + g * 4]) = qs;
    }
}

// ---------------- dst-grouped edge epilogue: 2 edges per wave ----------------
// lanes 0-31 = edge A (pos=base), 32-63 = edge B (pos=base+1). Same dst node.
// lane covers dims 4*hlane..4*hlane+3 of both P/Q (mean) and R/S (var) paths.
// writes raw (pm,pv) to tmp[pos]; bias+exp applied in permute_k.
__global__ __launch_bounds__(256) void edge_head3_k(
    const uint* __restrict__ PRb, const uint* __restrict__ QSb,
    const int* __restrict__ rowptr, const int* __restrict__ srclist,
    const float* __restrict__ Wm2, const float* __restrict__ Wv2,
    float2* __restrict__ tmp, int N)
{
    int gid   = blockIdx.x * 256 + threadIdx.x;
    int node  = gid >> 6;
    int lane  = gid & 63;
    int half  = lane >> 5;
    int hlane = lane & 31;
    if (node >= N) return;
    int beg = rowptr[node];
    int end = rowptr[node + 1];
    if (beg == end) return;

    uint4 qs4 = *reinterpret_cast<const uint4*>(&QSb[(size_t)node * 128 + hlane * 4]);
    float q0 = bflo(qs4.x), q1 = bfhi(qs4.x);
    float s0 = bflo(qs4.y), s1 = bfhi(qs4.y);
    float q2 = bflo(qs4.z), q3 = bfhi(qs4.z);
    float s2 = bflo(qs4.w), s3 = bfhi(qs4.w);

    float4 wm = *reinterpret_cast<const float4*>(&Wm2[hlane * 4]);
    float4 wv = *reinterpret_cast<const float4*>(&Wv2[hlane * 4]);

    for (int base = beg; base < end; base += 2) {
        int p  = base + half;
        int pc = min(p, end - 1);
        int src = srclist[pc];
        uint4 pr4 = *reinterpret_cast<const uint4*>(&PRb[(size_t)src * 128 + hlane * 4]);
        float P0 = bflo(pr4.x), P1 = bfhi(pr4.x);
        float R0 = bflo(pr4.y), R1 = bfhi(pr4.y);
        float P2 = bflo(pr4.z), P3 = bfhi(pr4.z);
        float R2 = bflo(pr4.w), R3 = bfhi(pr4.w);

        float pm = fmaf(fmaxf(P0 + q0, 0.f), wm.x,
                   fmaf(fmaxf(P1 + q1, 0.f), wm.y,
                   fmaf(fmaxf(P2 + q2, 0.f), wm.z,
                        fmaxf(P3 + q3, 0.f) * wm.w)));
        float pv = fmaf(fmaxf(R0 + s0, 0.f), wv.x,
                   fmaf(fmaxf(R1 + s1, 0.f), wv.y,
                   fmaf(fmaxf(R2 + s2, 0.f), wv.z,
                        fmaxf(R3 + s3, 0.f) * wv.w)));

        // combined 32-lane reduce: after xor-16, lanes {0-15}=pm pair-sums,
        // {16-31}=pv pair-sums; 4 more levels reduce both simultaneously.
        pm += __shfl_xor(pm, 16);
        pv += __shfl_xor(pv, 16);
        float c = (hlane & 16) ? pv : pm;
        c += __shfl_xor(c, 8);
        c += __shfl_xor(c, 4);
        c += __shfl_xor(c, 2);
        c += __shfl_xor(c, 1);
        float other = __shfl(c, (lane & 32) + 16);   // lane h*32+0 reads h*32+16
        if (hlane == 0 && p < end) tmp[p] = make_float2(c, other);
    }
}

// ---------------- CSR-order -> edge-order permute + bias + exp ----------------
__global__ __launch_bounds__(256) void permute_k(
    const float2* __restrict__ tmp, const int* __restrict__ invpos,
    const float* __restrict__ bm2, const float* __restrict__ bv2,
    float* __restrict__ mean_out, float* __restrict__ var_out, int E)
{
    int e = blockIdx.x * 256 + threadIdx.x;
    if (e >= E) return;
    float2 t = tmp[invpos[e]];
    mean_out[e] = t.x + bm2[0];
    var_out[e]  = expf(0.5f * (t.y + bv2[0]));
}

extern "C" void kernel_launch(void* const* d_in, const int* in_sizes, int n_in,
                              void* d_out, int out_size, void* d_ws, size_t ws_size,
                              hipStream_t stream)
{
    const float* x       = (const float*)d_in[0];
    const int*   ei      = (const int*)d_in[1];
    const float* W1_rel  = (const float*)d_in[2];
    const float* b1      = (const float*)d_in[3];
    const float* W1_root = (const float*)d_in[4];
    const float* W2_rel  = (const float*)d_in[5];
    const float* b2      = (const float*)d_in[6];
    const float* W2_root = (const float*)d_in[7];
    const float* Wm1     = (const float*)d_in[8];
    const float* bm1     = (const float*)d_in[9];
    const float* Wm2     = (const float*)d_in[10];
    const float* bm2     = (const float*)d_in[11];
    const float* Wv1     = (const float*)d_in[12];
    const float* bv1     = (const float*)d_in[13];
    const float* Wv2     = (const float*)d_in[14];
    const float* bv2     = (const float*)d_in[15];

    const int N = in_sizes[0] / NF;   // 50000
    const int E = in_sizes[1] / 2;    // 800000

    const size_t SZ16 = (size_t)N * NF * 2;       // 12.8 MB bf16 node table

    char* base = (char*)d_ws;
    // [0,S): x_b, later h2b | [S,2S): h1b | [2S,3S): AGGb | PRb = [S,3S) | QSb = [3S,5S)
    uint* x_b  = (uint*)(base);
    uint* h2b  = (uint*)(base);
    uint* h1b  = (uint*)(base + SZ16);
    uint* AGGb = (uint*)(base + 2 * SZ16);
    uint* PRb  = (uint*)(base + SZ16);
    uint* QSb  = (uint*)(base + 3 * SZ16);

    char* wts = base + 5 * SZ16;
    uint* wt[8];
    for (int i = 0; i < 8; ++i) wt[i] = (uint*)(wts + (size_t)i * 32768);

    char* csr = wts + 8 * 32768;
    int* deg     = (int*)(csr);
    int* rowptr  = (int*)(csr + (size_t)(N + 64) * 4);
    int* cursor  = (int*)(csr + (size_t)(N + 64) * 8);
    int* srclist = (int*)(csr + (size_t)(N + 64) * 12);
    int* invpos  = srclist + E;
    float2* tmp  = (float2*)(invpos + E);

    float* out_mean = (float*)d_out;
    float* out_var  = out_mean + E;

    dim3 blk(256);
    dim3 eGrid((E + 255) / 256);                             // 3125
    dim3 mfmaGrid((N + 63) / 64);                            // 782
    dim3 nodeGrid((unsigned)(((size_t)N * 64 + 255) / 256)); // 12500 (1 wave/node)
    dim3 node2Grid((unsigned)((((size_t)(N + 1) / 2) * 64 + 255) / 256)); // 2 nodes/wave

    // ---- cast x to bf16 table
    hipLaunchKernelGGL(cast_bf16_k, nodeGrid, blk, 0, stream, x, x_b, N * 64);

    // ---- pack all weights: WT[c][k] bf16
    W8 wp;
    wp.src[0] = W1_rel;            wp.dst[0] = wt[0];
    wp.src[1] = W1_root;           wp.dst[1] = wt[1];
    wp.src[2] = W2_rel;            wp.dst[2] = wt[2];
    wp.src[3] = W2_root;           wp.dst[3] = wt[3];
    wp.src[4] = Wm1;               wp.dst[4] = wt[4];   // P (src half)
    wp.src[5] = Wm1 + NF * NF;     wp.dst[5] = wt[5];   // Q (dst half)
    wp.src[6] = Wv1;               wp.dst[6] = wt[6];   // R
    wp.src[7] = Wv1 + NF * NF;     wp.dst[7] = wt[7];   // S
    hipLaunchKernelGGL(wtpack_k, dim3(32, 8), blk, 0, stream, wp);

    // ---- CSR build
    hipMemsetAsync(deg, 0, (size_t)N * 4, stream);
    hipLaunchKernelGGL(count_k, eGrid, blk, 0, stream, ei, deg, E);
    hipLaunchKernelGGL(scan_k, dim3(1), dim3(1024), 0, stream, deg, rowptr, cursor, N);
    hipLaunchKernelGGL(fill_k, eGrid, blk, 0, stream, ei, cursor, srclist, invpos, E);

    // ---- conv1: h1 = relu(segsum(x)@W1_rel + x@W1_root + b1)
    hipLaunchKernelGGL(agg2_k, node2Grid, blk, 0, stream, x_b, rowptr, srclist, AGGb, N);
    hipLaunchKernelGGL(dualgemm_mfma_k, mfmaGrid, blk, 0, stream,
                       AGGb, wt[0], x_b, wt[1], b1, h1b, N);

    // ---- conv2: h2 = relu(segsum(h1)@W2_rel + h1@W2_root + b2)  (h2b over x_b)
    hipLaunchKernelGGL(agg2_k, node2Grid, blk, 0, stream, h1b, rowptr, srclist, AGGb, N);
    hipLaunchKernelGGL(dualgemm_mfma_k, mfmaGrid, blk, 0, stream,
                       AGGb, wt[2], h1b, wt[3], b2, h2b, N);

    // ---- head precompute (PRb over h1b+AGGb; both dead now)
    hipLaunchKernelGGL(headgemm_mfma_k, mfmaGrid, blk, 0, stream,
                       h2b, wt[4], wt[5], wt[6], wt[7], bm1, bv1, PRb, QSb, N);

    // ---- dst-grouped per-edge epilogue (raw pm/pv into CSR-ordered tmp)
    hipLaunchKernelGGL(edge_head3_k, nodeGrid, blk, 0, stream,
                       PRb, QSb, rowptr, srclist, Wm2, Wv2, tmp, N);

    // ---- permute to edge order + bias + exp (coalesced output writes)
    hipLaunchKernelGGL(permute_k, eGrid, blk, 0, stream,
                       tmp, invpos, bm2, bv2, out_mean, out_var, E);
}

// Round 9
// 504.016 us; speedup vs baseline: 4.4169x; 1.1990x over previous
//
#include <hip/hip_runtime.h>
#include <cstdint>

#define NF 128

typedef unsigned int uint;
typedef short bf16x8 __attribute__((ext_vector_type(8)));
typedef float f32x4  __attribute__((ext_vector_type(4)));

__device__ __forceinline__ float2 ld2(const float* p) {
    return *reinterpret_cast<const float2*>(p);
}
// bf16 pair packed in a uint: elem0 = bits[15:0], elem1 = bits[31:16]
__device__ __forceinline__ float bflo(uint u) { return __uint_as_float(u << 16); }
__device__ __forceinline__ float bfhi(uint u) { return __uint_as_float(u & 0xffff0000u); }
__device__ __forceinline__ uint f2bf_rne(float f) {
    uint u = __float_as_uint(f);
    return (u + 0x7fffu + ((u >> 16) & 1u)) >> 16;
}
__device__ __forceinline__ uint pack2bf(float a, float b) {
    return f2bf_rne(a) | (f2bf_rne(b) << 16);
}

__device__ __forceinline__ bf16x8 ldfrag(const uint* __restrict__ tab, int idx, int kb, int g) {
    const uint4 u = *reinterpret_cast<const uint4*>(&tab[(size_t)idx * 64 + kb * 16 + g * 4]);
    union { uint4 u4; bf16x8 b; } c; c.u4 = u; return c.b;
}

// ---------------- fp32 -> bf16 table cast ----------------
__global__ __launch_bounds__(256) void cast_bf16_k(const float* __restrict__ in,
                                                   uint* __restrict__ out, int npairs)
{
    int i = blockIdx.x * 256 + threadIdx.x;
    if (i >= npairs) return;
    float2 v = ld2(&in[(size_t)i * 2]);
    out[i] = pack2bf(v.x, v.y);
}

// ---------------- weight transpose+cast: WT[c][k] = W[k][c], bf16-packed --------
struct W8 {
    const float* src[8];
    uint*        dst[8];
};
__global__ __launch_bounds__(256) void wtpack_k(W8 p)
{
    int m = blockIdx.y;
    const float* s = p.src[m];
    uint* d = p.dst[m];
    int idx = blockIdx.x * 256 + threadIdx.x;     // [0, 8192)
    int c   = idx >> 6;
    int kdw = idx & 63;
    float a = s[(size_t)(2 * kdw)     * NF + c];
    float b = s[(size_t)(2 * kdw + 1) * NF + c];
    d[(size_t)c * 64 + kdw] = pack2bf(a, b);
}

// ---------------- CSR build ----------------
__global__ __launch_bounds__(256) void count_k(const int* __restrict__ ei,
                                               int* __restrict__ deg, int E)
{
    int e = blockIdx.x * 256 + threadIdx.x;
    if (e >= E) return;
    atomicAdd(&deg[ei[E + e]], 1);
}

// ---- hierarchical exclusive scan over deg[N] -> rowptr/cursor ----
// pass 1: block-local exclusive prefix into rowptr[i], block total into bsum[b]
__global__ __launch_bounds__(256) void scan1_k(const int* __restrict__ deg,
                                               int* __restrict__ rowptr,
                                               int* __restrict__ bsum, int N)
{
    int i = blockIdx.x * 256 + threadIdx.x;
    int v = (i < N) ? deg[i] : 0;
    int lane = threadIdx.x & 63;
    int wid  = threadIdx.x >> 6;
    int x = v;
#pragma unroll
    for (int off = 1; off < 64; off <<= 1) {
        int y = __shfl_up(x, off);
        if (lane >= off) x += y;
    }
    __shared__ int wsum[4];
    if (lane == 63) wsum[wid] = x;
    __syncthreads();
    int wadd = 0;
#pragma unroll
    for (int w = 0; w < 4; ++w) wadd += (w < wid) ? wsum[w] : 0;
    int incl = x + wadd;
    if (i < N) rowptr[i] = incl - v;                 // block-local exclusive
    if (threadIdx.x == 255) bsum[blockIdx.x] = incl; // block total
}

// pass 2: single block exclusive-scans bsum[NB] in place (NB <= 256)
__global__ __launch_bounds__(256) void scan2_k(int* __restrict__ bsum, int NB)
{
    int i = threadIdx.x;
    int v = (i < NB) ? bsum[i] : 0;
    int lane = threadIdx.x & 63;
    int wid  = threadIdx.x >> 6;
    int x = v;
#pragma unroll
    for (int off = 1; off < 64; off <<= 1) {
        int y = __shfl_up(x, off);
        if (lane >= off) x += y;
    }
    __shared__ int wsum[4];
    if (lane == 63) wsum[wid] = x;
    __syncthreads();
    int wadd = 0;
#pragma unroll
    for (int w = 0; w < 4; ++w) wadd += (w < wid) ? wsum[w] : 0;
    int incl = x + wadd;
    __syncthreads();
    if (i < NB) bsum[i] = incl - v;                  // exclusive block offsets
}

// pass 3: add block offsets; mirror into cursor; rowptr[N] = E
__global__ __launch_bounds__(256) void scan3_k(const int* __restrict__ bsum,
                                               int* __restrict__ rowptr,
                                               int* __restrict__ cursor, int N, int E)
{
    int i = blockIdx.x * 256 + threadIdx.x;
    if (i == 0) rowptr[N] = E;
    if (i >= N) return;
    int r = rowptr[i] + bsum[blockIdx.x];
    rowptr[i] = r;
    cursor[i] = r;
}

// srclist[pos]=src (scattered), invpos[e]=pos (coalesced)
__global__ __launch_bounds__(256) void fill_k(const int* __restrict__ ei,
                                              int* __restrict__ cursor,
                                              int* __restrict__ srclist,
                                              int* __restrict__ invpos, int E)
{
    int e = blockIdx.x * 256 + threadIdx.x;
    if (e >= E) return;
    int s = ei[e];
    int d = ei[E + e];
    int pos = atomicAdd(&cursor[d], 1);
    srclist[pos] = s;
    invpos[e] = pos;
}

// ---------------- aggregation: 2 nodes per wave, 32 lanes each ----------------
__global__ __launch_bounds__(256) void agg2_k(const uint* __restrict__ Xb,
                                              const int* __restrict__ rowptr,
                                              const int* __restrict__ srclist,
                                              uint* __restrict__ AGGb, int N)
{
    int gid   = blockIdx.x * 256 + threadIdx.x;
    int wave  = gid >> 6;
    int lane  = gid & 63;
    int half  = lane >> 5;
    int hlane = lane & 31;
    int node  = wave * 2 + half;
    int nc    = min(node, N - 1);
    int beg = rowptr[nc];
    int end = rowptr[nc + 1];
    if (node >= N) { beg = 0; end = 0; }

    float ax = 0.f, ay = 0.f, az = 0.f, aw = 0.f;
    float bx = 0.f, by = 0.f, bz = 0.f, bw = 0.f;
    for (int j = beg; j < end; j += 2) {
        int  ok1 = (j + 1 < end);
        int  s0 = srclist[j];
        int  s1 = ok1 ? srclist[j + 1] : s0;
        uint2 w0 = *reinterpret_cast<const uint2*>(&Xb[(size_t)s0 * 64 + hlane * 2]);
        uint2 w1 = *reinterpret_cast<const uint2*>(&Xb[(size_t)s1 * 64 + hlane * 2]);
        ax += bflo(w0.x); ay += bfhi(w0.x); az += bflo(w0.y); aw += bfhi(w0.y);
        if (ok1) { bx += bflo(w1.x); by += bfhi(w1.x); bz += bflo(w1.y); bw += bfhi(w1.y); }
    }
    if (node < N) {
        uint2 o;
        o.x = pack2bf(ax + bx, ay + by);
        o.y = pack2bf(az + bz, aw + bw);
        *reinterpret_cast<uint2*>(&AGGb[(size_t)node * 64 + hlane * 2]) = o;
    }
}

// ---------------- MFMA dual GEMM: C = bf16(relu(Aa@Wa + Ab@Wb + bias)) --------
__global__ __launch_bounds__(256) void dualgemm_mfma_k(
    const uint* __restrict__ Aa, const uint* __restrict__ WaT,
    const uint* __restrict__ Ab, const uint* __restrict__ WbT,
    const float* __restrict__ bias, uint* __restrict__ C, int Nrows)
{
    const int lane = threadIdx.x & 63;
    const int wid  = threadIdx.x >> 6;
    const int g    = lane >> 4;
    const int r15  = lane & 15;
    const int rowBase = blockIdx.x * 64 + wid * 16;
    if (rowBase >= Nrows) return;
    const int arow = rowBase + r15;

    bf16x8 ba[4], bb[4];
#pragma unroll
    for (int kb = 0; kb < 4; ++kb) {
        ba[kb] = ldfrag(Aa, arow, kb, g);
        bb[kb] = ldfrag(Ab, arow, kb, g);
    }

#pragma unroll
    for (int ct = 0; ct < 8; ++ct) {
        const int wcol = ct * 16 + r15;
        f32x4 acc = {0.f, 0.f, 0.f, 0.f};
#pragma unroll
        for (int kb = 0; kb < 4; ++kb)
            acc = __builtin_amdgcn_mfma_f32_16x16x32_bf16(ldfrag(WaT, wcol, kb, g), ba[kb], acc, 0, 0, 0);
#pragma unroll
        for (int kb = 0; kb < 4; ++kb)
            acc = __builtin_amdgcn_mfma_f32_16x16x32_bf16(ldfrag(WbT, wcol, kb, g), bb[kb], acc, 0, 0, 0);

        const int colBase = ct * 16 + g * 4;
        float4 bs = *reinterpret_cast<const float4*>(&bias[colBase]);
        float v0 = fmaxf(acc[0] + bs.x, 0.f);
        float v1 = fmaxf(acc[1] + bs.y, 0.f);
        float v2 = fmaxf(acc[2] + bs.z, 0.f);
        float v3 = fmaxf(acc[3] + bs.w, 0.f);
        uint2 pk;
        pk.x = pack2bf(v0, v1);
        pk.y = pack2bf(v2, v3);
        *reinterpret_cast<uint2*>(&C[(size_t)arow * 64 + ct * 8 + g * 2]) = pk;
    }
}

// ---------------- MFMA head GEMM: PRb/QSb interleaved bf16 tables --------------
__global__ __launch_bounds__(256) void headgemm_mfma_k(
    const uint* __restrict__ Hb,
    const uint* __restrict__ WPt, const uint* __restrict__ WQt,
    const uint* __restrict__ WRt, const uint* __restrict__ WSt,
    const float* __restrict__ bm1, const float* __restrict__ bv1,
    uint* __restrict__ PRb, uint* __restrict__ QSb, int Nrows)
{
    const int lane = threadIdx.x & 63;
    const int wid  = threadIdx.x >> 6;
    const int g    = lane >> 4;
    const int r15  = lane & 15;
    const int rowBase = blockIdx.x * 64 + wid * 16;
    if (rowBase >= Nrows) return;
    const int arow = rowBase + r15;

    bf16x8 hb[4];
#pragma unroll
    for (int kb = 0; kb < 4; ++kb) hb[kb] = ldfrag(Hb, arow, kb, g);

#pragma unroll
    for (int ct = 0; ct < 8; ++ct) {
        const int wcol = ct * 16 + r15;
        f32x4 aP = {0.f,0.f,0.f,0.f}, aQ = {0.f,0.f,0.f,0.f};
        f32x4 aR = {0.f,0.f,0.f,0.f}, aS = {0.f,0.f,0.f,0.f};
#pragma unroll
        for (int kb = 0; kb < 4; ++kb) {
            aP = __builtin_amdgcn_mfma_f32_16x16x32_bf16(ldfrag(WPt, wcol, kb, g), hb[kb], aP, 0, 0, 0);
            aQ = __builtin_amdgcn_mfma_f32_16x16x32_bf16(ldfrag(WQt, wcol, kb, g), hb[kb], aQ, 0, 0, 0);
            aR = __builtin_amdgcn_mfma_f32_16x16x32_bf16(ldfrag(WRt, wcol, kb, g), hb[kb], aR, 0, 0, 0);
            aS = __builtin_amdgcn_mfma_f32_16x16x32_bf16(ldfrag(WSt, wcol, kb, g), hb[kb], aS, 0, 0, 0);
        }
        const int colBase = ct * 16 + g * 4;
        float4 bmv = *reinterpret_cast<const float4*>(&bm1[colBase]);
        float4 bvv = *reinterpret_cast<const float4*>(&bv1[colBase]);
        float p0 = aP[0] + bmv.x, p1 = aP[1] + bmv.y, p2 = aP[2] + bmv.z, p3 = aP[3] + bmv.w;
        float r0 = aR[0] + bvv.x, r1 = aR[1] + bvv.y, r2 = aR[2] + bvv.z, r3 = aR[3] + bvv.w;
        uint4 pr, qs;
        pr.x = pack2bf(p0, p1);     pr.y = pack2bf(r0, r1);
        pr.z = pack2bf(p2, p3);     pr.w = pack2bf(r2, r3);
        qs.x = pack2bf(aQ[0], aQ[1]); qs.y = pack2bf(aS[0], aS[1]);
        qs.z = pack2bf(aQ[2], aQ[3]); qs.w = pack2bf(aS[2], aS[3]);
        *reinterpret_cast<uint4*>(&PRb[(size_t)arow * 128 + ct * 16 + g * 4]) = pr;
        *reinterpret_cast<uint4*>(&QSb[(size_t)arow * 128 + ct * 16 + g * 4]) = qs;
    }
}

// ---------------- dst-grouped edge epilogue: 2 edges per wave ----------------
__global__ __launch_bounds__(256) void edge_head3_k(
    const uint* __restrict__ PRb, const uint* __restrict__ QSb,
    const int* __restrict__ rowptr, const int* __restrict__ srclist,
    const float* __restrict__ Wm2, const float* __restrict__ Wv2,
    float2* __restrict__ tmp, int N)
{
    int gid   = blockIdx.x * 256 + threadIdx.x;
    int node  = gid >> 6;
    int lane  = gid & 63;
    int half  = lane >> 5;
    int hlane = lane & 31;
    if (node >= N) return;
    int beg = rowptr[node];
    int end = rowptr[node + 1];
    if (beg == end) return;

    uint4 qs4 = *reinterpret_cast<const uint4*>(&QSb[(size_t)node * 128 + hlane * 4]);
    float q0 = bflo(qs4.x), q1 = bfhi(qs4.x);
    float s0 = bflo(qs4.y), s1 = bfhi(qs4.y);
    float q2 = bflo(qs4.z), q3 = bfhi(qs4.z);
    float s2 = bflo(qs4.w), s3 = bfhi(qs4.w);

    float4 wm = *reinterpret_cast<const float4*>(&Wm2[hlane * 4]);
    float4 wv = *reinterpret_cast<const float4*>(&Wv2[hlane * 4]);

    for (int base = beg; base < end; base += 2) {
        int p  = base + half;
        int pc = min(p, end - 1);
        int src = srclist[pc];
        uint4 pr4 = *reinterpret_cast<const uint4*>(&PRb[(size_t)src * 128 + hlane * 4]);
        float P0 = bflo(pr4.x), P1 = bfhi(pr4.x);
        float R0 = bflo(pr4.y), R1 = bfhi(pr4.y);
        float P2 = bflo(pr4.z), P3 = bfhi(pr4.z);
        float R2 = bflo(pr4.w), R3 = bfhi(pr4.w);

        float pm = fmaf(fmaxf(P0 + q0, 0.f), wm.x,
                   fmaf(fmaxf(P1 + q1, 0.f), wm.y,
                   fmaf(fmaxf(P2 + q2, 0.f), wm.z,
                        fmaxf(P3 + q3, 0.f) * wm.w)));
        float pv = fmaf(fmaxf(R0 + s0, 0.f), wv.x,
                   fmaf(fmaxf(R1 + s1, 0.f), wv.y,
                   fmaf(fmaxf(R2 + s2, 0.f), wv.z,
                        fmaxf(R3 + s3, 0.f) * wv.w)));

        pm += __shfl_xor(pm, 16);
        pv += __shfl_xor(pv, 16);
        float c = (hlane & 16) ? pv : pm;
        c += __shfl_xor(c, 8);
        c += __shfl_xor(c, 4);
        c += __shfl_xor(c, 2);
        c += __shfl_xor(c, 1);
        float other = __shfl(c, (lane & 32) + 16);
        if (hlane == 0 && p < end) tmp[p] = make_float2(c, other);
    }
}

// ---------------- CSR-order -> edge-order permute + bias + exp ----------------
__global__ __launch_bounds__(256) void permute_k(
    const float2* __restrict__ tmp, const int* __restrict__ invpos,
    const float* __restrict__ bm2, const float* __restrict__ bv2,
    float* __restrict__ mean_out, float* __restrict__ var_out, int E)
{
    int e = blockIdx.x * 256 + threadIdx.x;
    if (e >= E) return;
    float2 t = tmp[invpos[e]];
    mean_out[e] = t.x + bm2[0];
    var_out[e]  = expf(0.5f * (t.y + bv2[0]));
}

extern "C" void kernel_launch(void* const* d_in, const int* in_sizes, int n_in,
                              void* d_out, int out_size, void* d_ws, size_t ws_size,
                              hipStream_t stream)
{
    const float* x       = (const float*)d_in[0];
    const int*   ei      = (const int*)d_in[1];
    const float* W1_rel  = (const float*)d_in[2];
    const float* b1      = (const float*)d_in[3];
    const float* W1_root = (const float*)d_in[4];
    const float* W2_rel  = (const float*)d_in[5];
    const float* b2      = (const float*)d_in[6];
    const float* W2_root = (const float*)d_in[7];
    const float* Wm1     = (const float*)d_in[8];
    const float* bm1     = (const float*)d_in[9];
    const float* Wm2     = (const float*)d_in[10];
    const float* bm2     = (const float*)d_in[11];
    const float* Wv1     = (const float*)d_in[12];
    const float* bv1     = (const float*)d_in[13];
    const float* Wv2     = (const float*)d_in[14];
    const float* bv2     = (const float*)d_in[15];

    const int N = in_sizes[0] / NF;   // 50000
    const int E = in_sizes[1] / 2;    // 800000

    const size_t SZ16 = (size_t)N * NF * 2;       // 12.8 MB bf16 node table

    char* base = (char*)d_ws;
    uint* x_b  = (uint*)(base);
    uint* h2b  = (uint*)(base);
    uint* h1b  = (uint*)(base + SZ16);
    uint* AGGb = (uint*)(base + 2 * SZ16);
    uint* PRb  = (uint*)(base + SZ16);
    uint* QSb  = (uint*)(base + 3 * SZ16);

    char* wts = base + 5 * SZ16;
    uint* wt[8];
    for (int i = 0; i < 8; ++i) wt[i] = (uint*)(wts + (size_t)i * 32768);

    char* csr = wts + 8 * 32768;
    int* deg     = (int*)(csr);
    int* rowptr  = (int*)(csr + (size_t)(N + 64) * 4);
    int* cursor  = (int*)(csr + (size_t)(N + 64) * 8);
    int* srclist = (int*)(csr + (size_t)(N + 64) * 12);
    int* invpos  = srclist + E;
    float2* tmp  = (float2*)(invpos + E);
    int* bsum    = (int*)(tmp + E);

    float* out_mean = (float*)d_out;
    float* out_var  = out_mean + E;

    dim3 blk(256);
    dim3 eGrid((E + 255) / 256);                             // 3125
    dim3 mfmaGrid((N + 63) / 64);                            // 782
    dim3 nodeGrid((unsigned)(((size_t)N * 64 + 255) / 256)); // 12500 (1 wave/node)
    dim3 node2Grid((unsigned)((((size_t)(N + 1) / 2) * 64 + 255) / 256)); // 2 nodes/wave
    const int NB = (N + 255) / 256;                          // 196 scan blocks
    dim3 scanGrid(NB);

    // ---- cast x to bf16 table
    hipLaunchKernelGGL(cast_bf16_k, nodeGrid, blk, 0, stream, x, x_b, N * 64);

    // ---- pack all weights: WT[c][k] bf16
    W8 wp;
    wp.src[0] = W1_rel;            wp.dst[0] = wt[0];
    wp.src[1] = W1_root;           wp.dst[1] = wt[1];
    wp.src[2] = W2_rel;            wp.dst[2] = wt[2];
    wp.src[3] = W2_root;           wp.dst[3] = wt[3];
    wp.src[4] = Wm1;               wp.dst[4] = wt[4];
    wp.src[5] = Wm1 + NF * NF;     wp.dst[5] = wt[5];
    wp.src[6] = Wv1;               wp.dst[6] = wt[6];
    wp.src[7] = Wv1 + NF * NF;     wp.dst[7] = wt[7];
    hipLaunchKernelGGL(wtpack_k, dim3(32, 8), blk, 0, stream, wp);

    // ---- CSR build (hierarchical scan)
    hipMemsetAsync(deg, 0, (size_t)N * 4, stream);
    hipLaunchKernelGGL(count_k, eGrid, blk, 0, stream, ei, deg, E);
    hipLaunchKernelGGL(scan1_k, scanGrid, blk, 0, stream, deg, rowptr, bsum, N);
    hipLaunchKernelGGL(scan2_k, dim3(1), blk, 0, stream, bsum, NB);
    hipLaunchKernelGGL(scan3_k, scanGrid, blk, 0, stream, bsum, rowptr, cursor, N, E);
    hipLaunchKernelGGL(fill_k, eGrid, blk, 0, stream, ei, cursor, srclist, invpos, E);

    // ---- conv1
    hipLaunchKernelGGL(agg2_k, node2Grid, blk, 0, stream, x_b, rowptr, srclist, AGGb, N);
    hipLaunchKernelGGL(dualgemm_mfma_k, mfmaGrid, blk, 0, stream,
                       AGGb, wt[0], x_b, wt[1], b1, h1b, N);

    // ---- conv2 (h2b over x_b)
    hipLaunchKernelGGL(agg2_k, node2Grid, blk, 0, stream, h1b, rowptr, srclist, AGGb, N);
    hipLaunchKernelGGL(dualgemm_mfma_k, mfmaGrid, blk, 0, stream,
                       AGGb, wt[2], h1b, wt[3], b2, h2b, N);

    // ---- head precompute
    hipLaunchKernelGGL(headgemm_mfma_k, mfmaGrid, blk, 0, stream,
                       h2b, wt[4], wt[5], wt[6], wt[7], bm1, bv1, PRb, QSb, N);

    // ---- dst-grouped per-edge epilogue (raw pm/pv into CSR-ordered tmp)
    hipLaunchKernelGGL(edge_head3_k, nodeGrid, blk, 0, stream,
                       PRb, QSb, rowptr, srclist, Wm2, Wv2, tmp, N);

    // ---- permute to edge order + bias + exp
    hipLaunchKernelGGL(permute_k, eGrid, blk, 0, stream,
                       tmp, invpos, bm2, bv2, out_mean, out_var, E);
}

// Round 11
// 450.417 us; speedup vs baseline: 4.9426x; 1.1190x over previous
//
#include <hip/hip_runtime.h>
#include <cstdint>

#define NF 128

typedef unsigned int uint;
typedef short bf16x8 __attribute__((ext_vector_type(8)));
typedef float f32x4  __attribute__((ext_vector_type(4)));

__device__ __forceinline__ float2 ld2(const float* p) {
    return *reinterpret_cast<const float2*>(p);
}
__device__ __forceinline__ float bflo(uint u) { return __uint_as_float(u << 16); }
__device__ __forceinline__ float bfhi(uint u) { return __uint_as_float(u & 0xffff0000u); }
__device__ __forceinline__ uint f2bf_rne(float f) {
    uint u = __float_as_uint(f);
    return (u + 0x7fffu + ((u >> 16) & 1u)) >> 16;
}
__device__ __forceinline__ uint pack2bf(float a, float b) {
    return f2bf_rne(a) | (f2bf_rne(b) << 16);
}

__device__ __forceinline__ bf16x8 ldfrag(const uint* __restrict__ tab, int idx, int kb, int g) {
    const uint4 u = *reinterpret_cast<const uint4*>(&tab[(size_t)idx * 64 + kb * 16 + g * 4]);
    union { uint4 u4; bf16x8 b; } c; c.u4 = u; return c.b;
}

// ---------------- fp32 -> bf16 table cast ----------------
__global__ __launch_bounds__(256) void cast_bf16_k(const float* __restrict__ in,
                                                   uint* __restrict__ out, int npairs)
{
    int i = blockIdx.x * 256 + threadIdx.x;
    if (i >= npairs) return;
    float2 v = ld2(&in[(size_t)i * 2]);
    out[i] = pack2bf(v.x, v.y);
}

// ---------------- weight transpose+cast ----------------
struct W8 {
    const float* src[8];
    uint*        dst[8];
};
__global__ __launch_bounds__(256) void wtpack_k(W8 p)
{
    int m = blockIdx.y;
    const float* s = p.src[m];
    uint* d = p.dst[m];
    int idx = blockIdx.x * 256 + threadIdx.x;
    int c   = idx >> 6;
    int kdw = idx & 63;
    float a = s[(size_t)(2 * kdw)     * NF + c];
    float b = s[(size_t)(2 * kdw + 1) * NF + c];
    d[(size_t)c * 64 + kdw] = pack2bf(a, b);
}

// ---------------- CSR build ----------------
__global__ __launch_bounds__(256) void count_k(const int* __restrict__ ei,
                                               int* __restrict__ deg, int E)
{
    int e = blockIdx.x * 256 + threadIdx.x;
    if (e >= E) return;
    atomicAdd(&deg[ei[E + e]], 1);
}

__global__ __launch_bounds__(256) void scan1_k(const int* __restrict__ deg,
                                               int* __restrict__ rowptr,
                                               int* __restrict__ bsum, int N)
{
    int i = blockIdx.x * 256 + threadIdx.x;
    int v = (i < N) ? deg[i] : 0;
    int lane = threadIdx.x & 63;
    int wid  = threadIdx.x >> 6;
    int x = v;
#pragma unroll
    for (int off = 1; off < 64; off <<= 1) {
        int y = __shfl_up(x, off);
        if (lane >= off) x += y;
    }
    __shared__ int wsum[4];
    if (lane == 63) wsum[wid] = x;
    __syncthreads();
    int wadd = 0;
#pragma unroll
    for (int w = 0; w < 4; ++w) wadd += (w < wid) ? wsum[w] : 0;
    int incl = x + wadd;
    if (i < N) rowptr[i] = incl - v;
    if (threadIdx.x == 255) bsum[blockIdx.x] = incl;
}

__global__ __launch_bounds__(256) void scan2_k(int* __restrict__ bsum, int NB)
{
    int i = threadIdx.x;
    int v = (i < NB) ? bsum[i] : 0;
    int lane = threadIdx.x & 63;
    int wid  = threadIdx.x >> 6;
    int x = v;
#pragma unroll
    for (int off = 1; off < 64; off <<= 1) {
        int y = __shfl_up(x, off);
        if (lane >= off) x += y;
    }
    __shared__ int wsum[4];
    if (lane == 63) wsum[wid] = x;
    __syncthreads();
    int wadd = 0;
#pragma unroll
    for (int w = 0; w < 4; ++w) wadd += (w < wid) ? wsum[w] : 0;
    int incl = x + wadd;
    __syncthreads();
    if (i < NB) bsum[i] = incl - v;
}

__global__ __launch_bounds__(256) void scan3_k(const int* __restrict__ bsum,
                                               int* __restrict__ rowptr,
                                               int* __restrict__ cursor, int N, int E)
{
    int i = blockIdx.x * 256 + threadIdx.x;
    if (i == 0) rowptr[N] = E;
    if (i >= N) return;
    int r = rowptr[i] + bsum[blockIdx.x];
    rowptr[i] = r;
    cursor[i] = r;
}

__global__ __launch_bounds__(256) void fill_k(const int* __restrict__ ei,
                                              int* __restrict__ cursor,
                                              int* __restrict__ srclist,
                                              int* __restrict__ invpos, int E)
{
    int e = blockIdx.x * 256 + threadIdx.x;
    if (e >= E) return;
    int s = ei[e];
    int d = ei[E + e];
    int pos = atomicAdd(&cursor[d], 1);
    srclist[pos] = s;
    invpos[e] = pos;
}

// ---------------- aggregation: 2 nodes/wave, software-pipelined gather --------
__global__ __launch_bounds__(256) void agg2_k(const uint* __restrict__ Xb,
                                              const int* __restrict__ rowptr,
                                              const int* __restrict__ srclist,
                                              uint* __restrict__ AGGb, int N)
{
    int gid   = blockIdx.x * 256 + threadIdx.x;
    int wave  = gid >> 6;
    int lane  = gid & 63;
    int half  = lane >> 5;
    int hlane = lane & 31;
    int node  = wave * 2 + half;
    int nc    = min(node, N - 1);
    int beg = rowptr[nc];
    int end = rowptr[nc + 1];
    if (node >= N) { beg = 0; end = 0; }

    float ax = 0.f, ay = 0.f, az = 0.f, aw = 0.f;
    float bx = 0.f, by = 0.f, bz = 0.f, bw = 0.f;

    uint2 w0 = make_uint2(0, 0), w1 = make_uint2(0, 0);
    int ok1 = 0;
    if (beg < end) {
        int s0 = srclist[beg];
        ok1 = (beg + 1 < end);
        int s1 = ok1 ? srclist[beg + 1] : s0;
        w0 = *reinterpret_cast<const uint2*>(&Xb[(size_t)s0 * 64 + hlane * 2]);
        w1 = *reinterpret_cast<const uint2*>(&Xb[(size_t)s1 * 64 + hlane * 2]);
    }
    for (int j = beg; j < end; j += 2) {
        int jn = j + 2;
        uint2 nw0 = w0, nw1 = w1;
        int nok1 = 0;
        if (jn < end) {
            int s0 = srclist[jn];
            nok1 = (jn + 1 < end);
            int s1 = nok1 ? srclist[jn + 1] : s0;
            nw0 = *reinterpret_cast<const uint2*>(&Xb[(size_t)s0 * 64 + hlane * 2]);
            nw1 = *reinterpret_cast<const uint2*>(&Xb[(size_t)s1 * 64 + hlane * 2]);
        }
        ax += bflo(w0.x); ay += bfhi(w0.x); az += bflo(w0.y); aw += bfhi(w0.y);
        if (ok1) { bx += bflo(w1.x); by += bfhi(w1.x); bz += bflo(w1.y); bw += bfhi(w1.y); }
        w0 = nw0; w1 = nw1; ok1 = nok1;
    }
    if (node < N) {
        uint2 o;
        o.x = pack2bf(ax + bx, ay + by);
        o.y = pack2bf(az + bz, aw + bw);
        *reinterpret_cast<uint2*>(&AGGb[(size_t)node * 64 + hlane * 2]) = o;
    }
}

// ---------------- MFMA dual GEMM, 32 rows/wave (2 tiles) ----------------------
__global__ __launch_bounds__(256) void dualgemm_mfma_k(
    const uint* __restrict__ Aa, const uint* __restrict__ WaT,
    const uint* __restrict__ Ab, const uint* __restrict__ WbT,
    const float* __restrict__ bias, uint* __restrict__ C, int Nrows)
{
    const int lane = threadIdx.x & 63;
    const int wid  = threadIdx.x >> 6;
    const int g    = lane >> 4;
    const int r15  = lane & 15;
    const int rowBase = blockIdx.x * 128 + wid * 32;
    if (rowBase >= Nrows) return;
    const int arow0 = rowBase + r15;
    const int t1ok  = (rowBase + 16) < Nrows;
    const int arow1 = t1ok ? (rowBase + 16 + r15) : arow0;

    bf16x8 ba0[4], bb0[4], ba1[4], bb1[4];
#pragma unroll
    for (int kb = 0; kb < 4; ++kb) {
        ba0[kb] = ldfrag(Aa, arow0, kb, g);
        bb0[kb] = ldfrag(Ab, arow0, kb, g);
        ba1[kb] = ldfrag(Aa, arow1, kb, g);
        bb1[kb] = ldfrag(Ab, arow1, kb, g);
    }

#pragma unroll
    for (int ct = 0; ct < 8; ++ct) {
        const int wcol = ct * 16 + r15;
        f32x4 a0 = {0.f, 0.f, 0.f, 0.f};
        f32x4 a1 = {0.f, 0.f, 0.f, 0.f};
#pragma unroll
        for (int kb = 0; kb < 4; ++kb) {
            bf16x8 wf = ldfrag(WaT, wcol, kb, g);
            a0 = __builtin_amdgcn_mfma_f32_16x16x32_bf16(wf, ba0[kb], a0, 0, 0, 0);
            a1 = __builtin_amdgcn_mfma_f32_16x16x32_bf16(wf, ba1[kb], a1, 0, 0, 0);
        }
#pragma unroll
        for (int kb = 0; kb < 4; ++kb) {
            bf16x8 wf = ldfrag(WbT, wcol, kb, g);
            a0 = __builtin_amdgcn_mfma_f32_16x16x32_bf16(wf, bb0[kb], a0, 0, 0, 0);
            a1 = __builtin_amdgcn_mfma_f32_16x16x32_bf16(wf, bb1[kb], a1, 0, 0, 0);
        }

        const int colBase = ct * 16 + g * 4;
        float4 bs = *reinterpret_cast<const float4*>(&bias[colBase]);
        uint2 pk0, pk1;
        pk0.x = pack2bf(fmaxf(a0[0] + bs.x, 0.f), fmaxf(a0[1] + bs.y, 0.f));
        pk0.y = pack2bf(fmaxf(a0[2] + bs.z, 0.f), fmaxf(a0[3] + bs.w, 0.f));
        pk1.x = pack2bf(fmaxf(a1[0] + bs.x, 0.f), fmaxf(a1[1] + bs.y, 0.f));
        pk1.y = pack2bf(fmaxf(a1[2] + bs.z, 0.f), fmaxf(a1[3] + bs.w, 0.f));
        *reinterpret_cast<uint2*>(&C[(size_t)arow0 * 64 + ct * 8 + g * 2]) = pk0;
        if (t1ok)
            *reinterpret_cast<uint2*>(&C[(size_t)arow1 * 64 + ct * 8 + g * 2]) = pk1;
    }
}

// ---------------- MFMA head GEMM, 32 rows/wave (2 tiles) ----------------------
__global__ __launch_bounds__(256) void headgemm_mfma_k(
    const uint* __restrict__ Hb,
    const uint* __restrict__ WPt, const uint* __restrict__ WQt,
    const uint* __restrict__ WRt, const uint* __restrict__ WSt,
    const float* __restrict__ bm1, const float* __restrict__ bv1,
    uint* __restrict__ PRb, uint* __restrict__ QSb, int Nrows)
{
    const int lane = threadIdx.x & 63;
    const int wid  = threadIdx.x >> 6;
    const int g    = lane >> 4;
    const int r15  = lane & 15;
    const int rowBase = blockIdx.x * 128 + wid * 32;
    if (rowBase >= Nrows) return;
    const int arow0 = rowBase + r15;
    const int t1ok  = (rowBase + 16) < Nrows;
    const int arow1 = t1ok ? (rowBase + 16 + r15) : arow0;

    bf16x8 hb0[4], hb1[4];
#pragma unroll
    for (int kb = 0; kb < 4; ++kb) {
        hb0[kb] = ldfrag(Hb, arow0, kb, g);
        hb1[kb] = ldfrag(Hb, arow1, kb, g);
    }

#pragma unroll
    for (int ct = 0; ct < 8; ++ct) {
        const int wcol = ct * 16 + r15;
        f32x4 aP0 = {0.f,0.f,0.f,0.f}, aQ0 = {0.f,0.f,0.f,0.f};
        f32x4 aR0 = {0.f,0.f,0.f,0.f}, aS0 = {0.f,0.f,0.f,0.f};
        f32x4 aP1 = {0.f,0.f,0.f,0.f}, aQ1 = {0.f,0.f,0.f,0.f};
        f32x4 aR1 = {0.f,0.f,0.f,0.f}, aS1 = {0.f,0.f,0.f,0.f};
#pragma unroll
        for (int kb = 0; kb < 4; ++kb) {
            bf16x8 wP = ldfrag(WPt, wcol, kb, g);
            bf16x8 wQ = ldfrag(WQt, wcol, kb, g);
            bf16x8 wR = ldfrag(WRt, wcol, kb, g);
            bf16x8 wS = ldfrag(WSt, wcol, kb, g);
            aP0 = __builtin_amdgcn_mfma_f32_16x16x32_bf16(wP, hb0[kb], aP0, 0, 0, 0);
            aP1 = __builtin_amdgcn_mfma_f32_16x16x32_bf16(wP, hb1[kb], aP1, 0, 0, 0);
            aQ0 = __builtin_amdgcn_mfma_f32_16x16x32_bf16(wQ, hb0[kb], aQ0, 0, 0, 0);
            aQ1 = __builtin_amdgcn_mfma_f32_16x16x32_bf16(wQ, hb1[kb], aQ1, 0, 0, 0);
            aR0 = __builtin_amdgcn_mfma_f32_16x16x32_bf16(wR, hb0[kb], aR0, 0, 0, 0);
            aR1 = __builtin_amdgcn_mfma_f32_16x16x32_bf16(wR, hb1[kb], aR1, 0, 0, 0);
            aS0 = __builtin_amdgcn_mfma_f32_16x16x32_bf16(wS, hb0[kb], aS0, 0, 0, 0);
            aS1 = __builtin_amdgcn_mfma_f32_16x16x32_bf16(wS, hb1[kb], aS1, 0, 0, 0);
        }
        const int colBase = ct * 16 + g * 4;
        float4 bmv = *reinterpret_cast<const float4*>(&bm1[colBase]);
        float4 bvv = *reinterpret_cast<const float4*>(&bv1[colBase]);
        uint4 pr0, qs0, pr1, qs1;
        pr0.x = pack2bf(aP0[0] + bmv.x, aP0[1] + bmv.y);
        pr0.y = pack2bf(aR0[0] + bvv.x, aR0[1] + bvv.y);
        pr0.z = pack2bf(aP0[2] + bmv.z, aP0[3] + bmv.w);
        pr0.w = pack2bf(aR0[2] + bvv.z, aR0[3] + bvv.w);
        qs0.x = pack2bf(aQ0[0], aQ0[1]); qs0.y = pack2bf(aS0[0], aS0[1]);
        qs0.z = pack2bf(aQ0[2], aQ0[3]); qs0.w = pack2bf(aS0[2], aS0[3]);
        pr1.x = pack2bf(aP1[0] + bmv.x, aP1[1] + bmv.y);
        pr1.y = pack2bf(aR1[0] + bvv.x, aR1[1] + bvv.y);
        pr1.z = pack2bf(aP1[2] + bmv.z, aP1[3] + bmv.w);
        pr1.w = pack2bf(aR1[2] + bvv.z, aR1[3] + bvv.w);
        qs1.x = pack2bf(aQ1[0], aQ1[1]); qs1.y = pack2bf(aS1[0], aS1[1]);
        qs1.z = pack2bf(aQ1[2], aQ1[3]); qs1.w = pack2bf(aS1[2], aS1[3]);
        *reinterpret_cast<uint4*>(&PRb[(size_t)arow0 * 128 + ct * 16 + g * 4]) = pr0;
        *reinterpret_cast<uint4*>(&QSb[(size_t)arow0 * 128 + ct * 16 + g * 4]) = qs0;
        if (t1ok) {
            *reinterpret_cast<uint4*>(&PRb[(size_t)arow1 * 128 + ct * 16 + g * 4]) = pr1;
            *reinterpret_cast<uint4*>(&QSb[(size_t)arow1 * 128 + ct * 16 + g * 4]) = qs1;
        }
    }
}

// ---------------- dst-grouped edge epilogue: 2 edges/wave, pipelined ----------
__global__ __launch_bounds__(256) void edge_head3_k(
    const uint* __restrict__ PRb, const uint* __restrict__ QSb,
    const int* __restrict__ rowptr, const int* __restrict__ srclist,
    const float* __restrict__ Wm2, const float* __restrict__ Wv2,
    float2* __restrict__ tmp, int N)
{
    int gid   = blockIdx.x * 256 + threadIdx.x;
    int node  = gid >> 6;
    int lane  = gid & 63;
    int half  = lane >> 5;
    int hlane = lane & 31;
    if (node >= N) return;
    int beg = rowptr[node];
    int end = rowptr[node + 1];
    if (beg == end) return;

    uint4 qs4 = *reinterpret_cast<const uint4*>(&QSb[(size_t)node * 128 + hlane * 4]);
    float q0 = bflo(qs4.x), q1 = bfhi(qs4.x);
    float s0 = bflo(qs4.y), s1 = bfhi(qs4.y);
    float q2 = bflo(qs4.z), q3 = bfhi(qs4.z);
    float s2 = bflo(qs4.w), s3 = bfhi(qs4.w);

    float4 wm = *reinterpret_cast<const float4*>(&Wm2[hlane * 4]);
    float4 wv = *reinterpret_cast<const float4*>(&Wv2[hlane * 4]);

    // prologue: load first PR row
    int p0 = beg + half;
    int src0 = srclist[min(p0, end - 1)];
    uint4 pr_cur = *reinterpret_cast<const uint4*>(&PRb[(size_t)src0 * 128 + hlane * 4]);

    for (int base = beg; base < end; base += 2) {
        int p = base + half;
        // prefetch next iteration's PR row before the compute/reduce chain
        uint4 pr_next = pr_cur;
        if (base + 2 < end) {
            int pn = base + 2 + half;
            int srcn = srclist[min(pn, end - 1)];
            pr_next = *reinterpret_cast<const uint4*>(&PRb[(size_t)srcn * 128 + hlane * 4]);
        }

        float P0 = bflo(pr_cur.x), P1 = bfhi(pr_cur.x);
        float R0 = bflo(pr_cur.y), R1 = bfhi(pr_cur.y);
        float P2 = bflo(pr_cur.z), P3 = bfhi(pr_cur.z);
        float R2 = bflo(pr_cur.w), R3 = bfhi(pr_cur.w);

        float pm = fmaf(fmaxf(P0 + q0, 0.f), wm.x,
                   fmaf(fmaxf(P1 + q1, 0.f), wm.y,
                   fmaf(fmaxf(P2 + q2, 0.f), wm.z,
                        fmaxf(P3 + q3, 0.f) * wm.w)));
        float pv = fmaf(fmaxf(R0 + s0, 0.f), wv.x,
                   fmaf(fmaxf(R1 + s1, 0.f), wv.y,
                   fmaf(fmaxf(R2 + s2, 0.f), wv.z,
                        fmaxf(R3 + s3, 0.f) * wv.w)));

        pm += __shfl_xor(pm, 16);
        pv += __shfl_xor(pv, 16);
        float c = (hlane & 16) ? pv : pm;
        c += __shfl_xor(c, 8);
        c += __shfl_xor(c, 4);
        c += __shfl_xor(c, 2);
        c += __shfl_xor(c, 1);
        float other = __shfl(c, (lane & 32) + 16);
        if (hlane == 0 && p < end) tmp[p] = make_float2(c, other);

        pr_cur = pr_next;
    }
}

// ---------------- CSR-order -> edge-order permute + bias + exp ----------------
__global__ __launch_bounds__(256) void permute_k(
    const float2* __restrict__ tmp, const int* __restrict__ invpos,
    const float* __restrict__ bm2, const float* __restrict__ bv2,
    float* __restrict__ mean_out, float* __restrict__ var_out, int E)
{
    int e = blockIdx.x * 256 + threadIdx.x;
    if (e >= E) return;
    float2 t = tmp[invpos[e]];
    mean_out[e] = t.x + bm2[0];
    var_out[e]  = expf(0.5f * (t.y + bv2[0]));
}

extern "C" void kernel_launch(void* const* d_in, const int* in_sizes, int n_in,
                              void* d_out, int out_size, void* d_ws, size_t ws_size,
                              hipStream_t stream)
{
    const float* x       = (const float*)d_in[0];
    const int*   ei      = (const int*)d_in[1];
    const float* W1_rel  = (const float*)d_in[2];
    const float* b1      = (const float*)d_in[3];
    const float* W1_root = (const float*)d_in[4];
    const float* W2_rel  = (const float*)d_in[5];
    const float* b2      = (const float*)d_in[6];
    const float* W2_root = (const float*)d_in[7];
    const float* Wm1     = (const float*)d_in[8];
    const float* bm1     = (const float*)d_in[9];
    const float* Wm2     = (const float*)d_in[10];
    const float* bm2     = (const float*)d_in[11];
    const float* Wv1     = (const float*)d_in[12];
    const float* bv1     = (const float*)d_in[13];
    const float* Wv2     = (const float*)d_in[14];
    const float* bv2     = (const float*)d_in[15];

    const int N = in_sizes[0] / NF;   // 50000
    const int E = in_sizes[1] / 2;    // 800000

    const size_t SZ16 = (size_t)N * NF * 2;       // 12.8 MB bf16 node table

    char* base = (char*)d_ws;
    uint* x_b  = (uint*)(base);
    uint* h2b  = (uint*)(base);
    uint* h1b  = (uint*)(base + SZ16);
    uint* AGGb = (uint*)(base + 2 * SZ16);
    uint* PRb  = (uint*)(base + SZ16);
    uint* QSb  = (uint*)(base + 3 * SZ16);

    char* wts = base + 5 * SZ16;
    uint* wt[8];
    for (int i = 0; i < 8; ++i) wt[i] = (uint*)(wts + (size_t)i * 32768);

    char* csr = wts + 8 * 32768;
    int* deg     = (int*)(csr);
    int* rowptr  = (int*)(csr + (size_t)(N + 64) * 4);
    int* cursor  = (int*)(csr + (size_t)(N + 64) * 8);
    int* srclist = (int*)(csr + (size_t)(N + 64) * 12);
    int* invpos  = srclist + E;
    float2* tmp  = (float2*)(invpos + E);
    int* bsum    = (int*)(tmp + E);

    float* out_mean = (float*)d_out;
    float* out_var  = out_mean + E;

    dim3 blk(256);
    dim3 eGrid((E + 255) / 256);                             // 3125
    dim3 mfmaGrid((N + 127) / 128);                          // 391
    dim3 nodeGrid((unsigned)(((size_t)N * 64 + 255) / 256)); // 12500 (1 wave/node)
    dim3 node2Grid((unsigned)((((size_t)(N + 1) / 2) * 64 + 255) / 256)); // 2 nodes/wave
    const int NB = (N + 255) / 256;                          // 196 scan blocks
    dim3 scanGrid(NB);

    // ---- cast x to bf16 table
    hipLaunchKernelGGL(cast_bf16_k, nodeGrid, blk, 0, stream, x, x_b, N * 64);

    // ---- pack all weights: WT[c][k] bf16
    W8 wp;
    wp.src[0] = W1_rel;            wp.dst[0] = wt[0];
    wp.src[1] = W1_root;           wp.dst[1] = wt[1];
    wp.src[2] = W2_rel;            wp.dst[2] = wt[2];
    wp.src[3] = W2_root;           wp.dst[3] = wt[3];
    wp.src[4] = Wm1;               wp.dst[4] = wt[4];
    wp.src[5] = Wm1 + NF * NF;     wp.dst[5] = wt[5];
    wp.src[6] = Wv1;               wp.dst[6] = wt[6];
    wp.src[7] = Wv1 + NF * NF;     wp.dst[7] = wt[7];
    hipLaunchKernelGGL(wtpack_k, dim3(32, 8), blk, 0, stream, wp);

    // ---- CSR build (hierarchical scan)
    hipMemsetAsync(deg, 0, (size_t)N * 4, stream);
    hipLaunchKernelGGL(count_k, eGrid, blk, 0, stream, ei, deg, E);
    hipLaunchKernelGGL(scan1_k, scanGrid, blk, 0, stream, deg, rowptr, bsum, N);
    hipLaunchKernelGGL(scan2_k, dim3(1), blk, 0, stream, bsum, NB);
    hipLaunchKernelGGL(scan3_k, scanGrid, blk, 0, stream, bsum, rowptr, cursor, N, E);
    hipLaunchKernelGGL(fill_k, eGrid, blk, 0, stream, ei, cursor, srclist, invpos, E);

    // ---- conv1
    hipLaunchKernelGGL(agg2_k, node2Grid, blk, 0, stream, x_b, rowptr, srclist, AGGb, N);
    hipLaunchKernelGGL(dualgemm_mfma_k, mfmaGrid, blk, 0, stream,
                       AGGb, wt[0], x_b, wt[1], b1, h1b, N);

    // ---- conv2 (h2b over x_b)
    hipLaunchKernelGGL(agg2_k, node2Grid, blk, 0, stream, h1b, rowptr, srclist, AGGb, N);
    hipLaunchKernelGGL(dualgemm_mfma_k, mfmaGrid, blk, 0, stream,
                       AGGb, wt[2], h1b, wt[3], b2, h2b, N);

    // ---- head precompute
    hipLaunchKernelGGL(headgemm_mfma_k, mfmaGrid, blk, 0, stream,
                       h2b, wt[4], wt[5], wt[6], wt[7], bm1, bv1, PRb, QSb, N);

    // ---- dst-grouped per-edge epilogue (raw pm/pv into CSR-ordered tmp)
    hipLaunchKernelGGL(edge_head3_k, nodeGrid, blk, 0, stream,
                       PRb, QSb, rowptr, srclist, Wm2, Wv2, tmp, N);

    // ---- permute to edge order + bias + exp
    hipLaunchKernelGGL(permute_k, eGrid, blk, 0, stream,
                       tmp, invpos, bm2, bv2, out_mean, out_var, E);
}

// Round 15
// 440.015 us; speedup vs baseline: 5.0594x; 1.0236x over previous
//
#include <hip/hip_runtime.h>
#include <cstdint>

#define NF 128

typedef unsigned int uint;
typedef short bf16x8 __attribute__((ext_vector_type(8)));
typedef float f32x4  __attribute__((ext_vector_type(4)));

__device__ __forceinline__ float2 ld2(const float* p) {
    return *reinterpret_cast<const float2*>(p);
}
__device__ __forceinline__ float bflo(uint u) { return __uint_as_float(u << 16); }
__device__ __forceinline__ float bfhi(uint u) { return __uint_as_float(u & 0xffff0000u); }
__device__ __forceinline__ uint f2bf_rne(float f) {
    uint u = __float_as_uint(f);
    return (u + 0x7fffu + ((u >> 16) & 1u)) >> 16;
}
__device__ __forceinline__ uint pack2bf(float a, float b) {
    return f2bf_rne(a) | (f2bf_rne(b) << 16);
}

__device__ __forceinline__ bf16x8 ldfrag(const uint* __restrict__ tab, int idx, int kb, int g) {
    const uint4 u = *reinterpret_cast<const uint4*>(&tab[(size_t)idx * 64 + kb * 16 + g * 4]);
    union { uint4 u4; bf16x8 b; } c; c.u4 = u; return c.b;
}

// ---------------- fused prologue: x-cast | weight-pack | degree-count ----------
struct W8 {
    const float* src[8];
    uint*        dst[8];
};
__global__ __launch_bounds__(256) void prologue_k(
    const float* __restrict__ x, uint* __restrict__ x_b, int npairs, int castBlocks,
    W8 wp,
    const int* __restrict__ ei, int* __restrict__ deg, int E, int countBlocks)
{
    int b = blockIdx.x;
    if (b < castBlocks) {
        int i = b * 256 + threadIdx.x;
        if (i >= npairs) return;
        float2 v = ld2(&x[(size_t)i * 2]);
        x_b[i] = pack2bf(v.x, v.y);
    } else if (b < castBlocks + 256) {
        int wb = b - castBlocks;          // [0,256)
        int m  = wb >> 5;                 // 8 matrices
        int bx = wb & 31;
        const float* s = wp.src[m];
        uint* d = wp.dst[m];
        int idx = bx * 256 + threadIdx.x; // [0, 8192)
        int c   = idx >> 6;
        int kdw = idx & 63;
        float a  = s[(size_t)(2 * kdw)     * NF + c];
        float b2 = s[(size_t)(2 * kdw + 1) * NF + c];
        d[(size_t)c * 64 + kdw] = pack2bf(a, b2);
    } else {
        int e = (b - castBlocks - 256) * 256 + threadIdx.x;
        if (e >= E) return;
        atomicAdd(&deg[ei[E + e]], 1);
    }
}

// ---------------- CSR scan: pass 1 (block-local) ----------------
__global__ __launch_bounds__(256) void scan1_k(const int* __restrict__ deg,
                                               int* __restrict__ rowptr,
                                               int* __restrict__ bsum, int N)
{
    int i = blockIdx.x * 256 + threadIdx.x;
    int v = (i < N) ? deg[i] : 0;
    int lane = threadIdx.x & 63;
    int wid  = threadIdx.x >> 6;
    int x = v;
#pragma unroll
    for (int off = 1; off < 64; off <<= 1) {
        int y = __shfl_up(x, off);
        if (lane >= off) x += y;
    }
    __shared__ int wsum[4];
    if (lane == 63) wsum[wid] = x;
    __syncthreads();
    int wadd = 0;
#pragma unroll
    for (int w = 0; w < 4; ++w) wadd += (w < wid) ? wsum[w] : 0;
    int incl = x + wadd;
    if (i < N) rowptr[i] = incl - v;
    if (threadIdx.x == 255) bsum[blockIdx.x] = incl;
}

// ---------------- CSR scan: fused pass 2+3 ----------------
__global__ __launch_bounds__(256) void scan23_k(const int* __restrict__ bsum,
                                                int* __restrict__ rowptr,
                                                int* __restrict__ cursor, int N, int E)
{
    int tid = threadIdx.x;
    int v = (tid < blockIdx.x) ? bsum[tid] : 0;   // NB <= 256
    int lane = tid & 63;
    int wid  = tid >> 6;
#pragma unroll
    for (int off = 32; off > 0; off >>= 1) v += __shfl_xor(v, off);
    __shared__ int ws[4];
    if (lane == 0) ws[wid] = v;
    __syncthreads();
    int prefix = ws[0] + ws[1] + ws[2] + ws[3];

    if (blockIdx.x == 0 && tid == 0) rowptr[N] = E;
    int i = blockIdx.x * 256 + tid;
    if (i >= N) return;
    int r = rowptr[i] + prefix;
    rowptr[i] = r;
    cursor[i] = r;
}

__global__ __launch_bounds__(256) void fill_k(const int* __restrict__ ei,
                                              int* __restrict__ cursor,
                                              int* __restrict__ srclist,
                                              int* __restrict__ invpos, int E)
{
    int e = blockIdx.x * 256 + threadIdx.x;
    if (e >= E) return;
    int s = ei[e];
    int d = ei[E + e];
    int pos = atomicAdd(&cursor[d], 1);
    srclist[pos] = s;
    invpos[e] = pos;
}

// ---------------- aggregation: 2 nodes/wave, software-pipelined gather --------
__global__ __launch_bounds__(256) void agg2_k(const uint* __restrict__ Xb,
                                              const int* __restrict__ rowptr,
                                              const int* __restrict__ srclist,
                                              uint* __restrict__ AGGb, int N)
{
    int gid   = blockIdx.x * 256 + threadIdx.x;
    int wave  = gid >> 6;
    int lane  = gid & 63;
    int half  = lane >> 5;
    int hlane = lane & 31;
    int node  = wave * 2 + half;
    int nc    = min(node, N - 1);
    int beg = rowptr[nc];
    int end = rowptr[nc + 1];
    if (node >= N) { beg = 0; end = 0; }

    float ax = 0.f, ay = 0.f, az = 0.f, aw = 0.f;
    float bx = 0.f, by = 0.f, bz = 0.f, bw = 0.f;

    uint2 w0 = make_uint2(0, 0), w1 = make_uint2(0, 0);
    int ok1 = 0;
    if (beg < end) {
        int s0 = srclist[beg];
        ok1 = (beg + 1 < end);
        int s1 = ok1 ? srclist[beg + 1] : s0;
        w0 = *reinterpret_cast<const uint2*>(&Xb[(size_t)s0 * 64 + hlane * 2]);
        w1 = *reinterpret_cast<const uint2*>(&Xb[(size_t)s1 * 64 + hlane * 2]);
    }
    for (int j = beg; j < end; j += 2) {
        int jn = j + 2;
        uint2 nw0 = w0, nw1 = w1;
        int nok1 = 0;
        if (jn < end) {
            int s0 = srclist[jn];
            nok1 = (jn + 1 < end);
            int s1 = nok1 ? srclist[jn + 1] : s0;
            nw0 = *reinterpret_cast<const uint2*>(&Xb[(size_t)s0 * 64 + hlane * 2]);
            nw1 = *reinterpret_cast<const uint2*>(&Xb[(size_t)s1 * 64 + hlane * 2]);
        }
        ax += bflo(w0.x); ay += bfhi(w0.x); az += bflo(w0.y); aw += bfhi(w0.y);
        if (ok1) { bx += bflo(w1.x); by += bfhi(w1.x); bz += bflo(w1.y); bw += bfhi(w1.y); }
        w0 = nw0; w1 = nw1; ok1 = nok1;
    }
    if (node < N) {
        uint2 o;
        o.x = pack2bf(ax + bx, ay + by);
        o.y = pack2bf(az + bz, aw + bw);
        *reinterpret_cast<uint2*>(&AGGb[(size_t)node * 64 + hlane * 2]) = o;
    }
}

// ---------------- MFMA dual GEMM, 32 rows/wave (conv1; writes global) ---------
__global__ __launch_bounds__(256) void dualgemm_mfma_k(
    const uint* __restrict__ Aa, const uint* __restrict__ WaT,
    const uint* __restrict__ Ab, const uint* __restrict__ WbT,
    const float* __restrict__ bias, uint* __restrict__ C, int Nrows)
{
    const int lane = threadIdx.x & 63;
    const int wid  = threadIdx.x >> 6;
    const int g    = lane >> 4;
    const int r15  = lane & 15;
    const int rowBase = blockIdx.x * 128 + wid * 32;
    if (rowBase >= Nrows) return;
    const int arow0 = rowBase + r15;
    const int t1ok  = (rowBase + 16) < Nrows;
    const int arow1 = t1ok ? (rowBase + 16 + r15) : arow0;

    bf16x8 ba0[4], bb0[4], ba1[4], bb1[4];
#pragma unroll
    for (int kb = 0; kb < 4; ++kb) {
        ba0[kb] = ldfrag(Aa, arow0, kb, g);
        bb0[kb] = ldfrag(Ab, arow0, kb, g);
        ba1[kb] = ldfrag(Aa, arow1, kb, g);
        bb1[kb] = ldfrag(Ab, arow1, kb, g);
    }

#pragma unroll
    for (int ct = 0; ct < 8; ++ct) {
        const int wcol = ct * 16 + r15;
        f32x4 a0 = {0.f, 0.f, 0.f, 0.f};
        f32x4 a1 = {0.f, 0.f, 0.f, 0.f};
#pragma unroll
        for (int kb = 0; kb < 4; ++kb) {
            bf16x8 wf = ldfrag(WaT, wcol, kb, g);
            a0 = __builtin_amdgcn_mfma_f32_16x16x32_bf16(wf, ba0[kb], a0, 0, 0, 0);
            a1 = __builtin_amdgcn_mfma_f32_16x16x32_bf16(wf, ba1[kb], a1, 0, 0, 0);
        }
#pragma unroll
        for (int kb = 0; kb < 4; ++kb) {
            bf16x8 wf = ldfrag(WbT, wcol, kb, g);
            a0 = __builtin_amdgcn_mfma_f32_16x16x32_bf16(wf, bb0[kb], a0, 0, 0, 0);
            a1 = __builtin_amdgcn_mfma_f32_16x16x32_bf16(wf, bb1[kb], a1, 0, 0, 0);
        }

        const int colBase = ct * 16 + g * 4;
        float4 bs = *reinterpret_cast<const float4*>(&bias[colBase]);
        uint2 pk0, pk1;
        pk0.x = pack2bf(fmaxf(a0[0] + bs.x, 0.f), fmaxf(a0[1] + bs.y, 0.f));
        pk0.y = pack2bf(fmaxf(a0[2] + bs.z, 0.f), fmaxf(a0[3] + bs.w, 0.f));
        pk1.x = pack2bf(fmaxf(a1[0] + bs.x, 0.f), fmaxf(a1[1] + bs.y, 0.f));
        pk1.y = pack2bf(fmaxf(a1[2] + bs.z, 0.f), fmaxf(a1[3] + bs.w, 0.f));
        *reinterpret_cast<uint2*>(&C[(size_t)arow0 * 64 + ct * 8 + g * 2]) = pk0;
        if (t1ok)
            *reinterpret_cast<uint2*>(&C[(size_t)arow1 * 64 + ct * 8 + g * 2]) = pk1;
    }
}

// ---------------- fused conv2 + head: h2 staged in LDS ------------------------
#define LROW 72   // padded LDS row stride in dwords (16B-aligned rows, bank-spread)
__global__ __launch_bounds__(256) void conv2head_k(
    const uint* __restrict__ Aa, const uint* __restrict__ WaT,
    const uint* __restrict__ Ab, const uint* __restrict__ WbT,
    const float* __restrict__ bias,
    const uint* __restrict__ WPt, const uint* __restrict__ WQt,
    const uint* __restrict__ WRt, const uint* __restrict__ WSt,
    const float* __restrict__ bm1, const float* __restrict__ bv1,
    uint* __restrict__ PRb, uint* __restrict__ QSb, int Nrows)
{
    __shared__ uint h2s[128 * LROW];   // 36864 B

    const int lane = threadIdx.x & 63;
    const int wid  = threadIdx.x >> 6;
    const int g    = lane >> 4;
    const int r15  = lane & 15;
    const int rowBase = blockIdx.x * 128 + wid * 32;
    const int active = rowBase < Nrows;
    const int arow0 = rowBase + r15;
    const int t1ok  = active && ((rowBase + 16) < Nrows);
    const int arow1 = t1ok ? (rowBase + 16 + r15) : (active ? arow0 : 0);
    const int lrow0 = wid * 32 + r15;
    const int lrow1 = wid * 32 + 16 + r15;

    // ---- phase 1: conv2 dual GEMM -> LDS (packed bf16, same values as before)
    if (active) {
        bf16x8 ba0[4], bb0[4], ba1[4], bb1[4];
#pragma unroll
        for (int kb = 0; kb < 4; ++kb) {
            ba0[kb] = ldfrag(Aa, arow0, kb, g);
            bb0[kb] = ldfrag(Ab, arow0, kb, g);
            ba1[kb] = ldfrag(Aa, arow1, kb, g);
            bb1[kb] = ldfrag(Ab, arow1, kb, g);
        }
#pragma unroll
        for (int ct = 0; ct < 8; ++ct) {
            const int wcol = ct * 16 + r15;
            f32x4 a0 = {0.f, 0.f, 0.f, 0.f};
            f32x4 a1 = {0.f, 0.f, 0.f, 0.f};
#pragma unroll
            for (int kb = 0; kb < 4; ++kb) {
                bf16x8 wf = ldfrag(WaT, wcol, kb, g);
                a0 = __builtin_amdgcn_mfma_f32_16x16x32_bf16(wf, ba0[kb], a0, 0, 0, 0);
                a1 = __builtin_amdgcn_mfma_f32_16x16x32_bf16(wf, ba1[kb], a1, 0, 0, 0);
            }
#pragma unroll
            for (int kb = 0; kb < 4; ++kb) {
                bf16x8 wf = ldfrag(WbT, wcol, kb, g);
                a0 = __builtin_amdgcn_mfma_f32_16x16x32_bf16(wf, bb0[kb], a0, 0, 0, 0);
                a1 = __builtin_amdgcn_mfma_f32_16x16x32_bf16(wf, bb1[kb], a1, 0, 0, 0);
            }
            const int colBase = ct * 16 + g * 4;
            float4 bs = *reinterpret_cast<const float4*>(&bias[colBase]);
            uint2 pk0, pk1;
            pk0.x = pack2bf(fmaxf(a0[0] + bs.x, 0.f), fmaxf(a0[1] + bs.y, 0.f));
            pk0.y = pack2bf(fmaxf(a0[2] + bs.z, 0.f), fmaxf(a0[3] + bs.w, 0.f));
            pk1.x = pack2bf(fmaxf(a1[0] + bs.x, 0.f), fmaxf(a1[1] + bs.y, 0.f));
            pk1.y = pack2bf(fmaxf(a1[2] + bs.z, 0.f), fmaxf(a1[3] + bs.w, 0.f));
            *reinterpret_cast<uint2*>(&h2s[lrow0 * LROW + ct * 8 + g * 2]) = pk0;
            *reinterpret_cast<uint2*>(&h2s[lrow1 * LROW + ct * 8 + g * 2]) = pk1;
        }
    }
    __syncthreads();

    // ---- phase 2: head GEMM from LDS
    if (!active) return;
    bf16x8 hb0[4], hb1[4];
#pragma unroll
    for (int kb = 0; kb < 4; ++kb) {
        union { uint4 u4; bf16x8 b; } c0, c1;
        c0.u4 = *reinterpret_cast<const uint4*>(&h2s[lrow0 * LROW + kb * 16 + g * 4]);
        c1.u4 = *reinterpret_cast<const uint4*>(&h2s[lrow1 * LROW + kb * 16 + g * 4]);
        hb0[kb] = c0.b;
        hb1[kb] = c1.b;
    }

#pragma unroll
    for (int ct = 0; ct < 8; ++ct) {
        const int wcol = ct * 16 + r15;
        f32x4 aP0 = {0.f,0.f,0.f,0.f}, aQ0 = {0.f,0.f,0.f,0.f};
        f32x4 aR0 = {0.f,0.f,0.f,0.f}, aS0 = {0.f,0.f,0.f,0.f};
        f32x4 aP1 = {0.f,0.f,0.f,0.f}, aQ1 = {0.f,0.f,0.f,0.f};
        f32x4 aR1 = {0.f,0.f,0.f,0.f}, aS1 = {0.f,0.f,0.f,0.f};
#pragma unroll
        for (int kb = 0; kb < 4; ++kb) {
            bf16x8 wP = ldfrag(WPt, wcol, kb, g);
            bf16x8 wQ = ldfrag(WQt, wcol, kb, g);
            bf16x8 wR = ldfrag(WRt, wcol, kb, g);
            bf16x8 wS = ldfrag(WSt, wcol, kb, g);
            aP0 = __builtin_amdgcn_mfma_f32_16x16x32_bf16(wP, hb0[kb], aP0, 0, 0, 0);
            aP1 = __builtin_amdgcn_mfma_f32_16x16x32_bf16(wP, hb1[kb], aP1, 0, 0, 0);
            aQ0 = __builtin_amdgcn_mfma_f32_16x16x32_bf16(wQ, hb0[kb], aQ0, 0, 0, 0);
            aQ1 = __builtin_amdgcn_mfma_f32_16x16x32_bf16(wQ, hb1[kb], aQ1, 0, 0, 0);
            aR0 = __builtin_amdgcn_mfma_f32_16x16x32_bf16(wR, hb0[kb], aR0, 0, 0, 0);
            aR1 = __builtin_amdgcn_mfma_f32_16x16x32_bf16(wR, hb1[kb], aR1, 0, 0, 0);
            aS0 = __builtin_amdgcn_mfma_f32_16x16x32_bf16(wS, hb0[kb], aS0, 0, 0, 0);
            aS1 = __builtin_amdgcn_mfma_f32_16x16x32_bf16(wS, hb1[kb], aS1, 0, 0, 0);
        }
        const int colBase = ct * 16 + g * 4;
        float4 bmv = *reinterpret_cast<const float4*>(&bm1[colBase]);
        float4 bvv = *reinterpret_cast<const float4*>(&bv1[colBase]);
        uint4 pr0, qs0, pr1, qs1;
        pr0.x = pack2bf(aP0[0] + bmv.x, aP0[1] + bmv.y);
        pr0.y = pack2bf(aR0[0] + bvv.x, aR0[1] + bvv.y);
        pr0.z = pack2bf(aP0[2] + bmv.z, aP0[3] + bmv.w);
        pr0.w = pack2bf(aR0[2] + bvv.z, aR0[3] + bvv.w);
        qs0.x = pack2bf(aQ0[0], aQ0[1]); qs0.y = pack2bf(aS0[0], aS0[1]);
        qs0.z = pack2bf(aQ0[2], aQ0[3]); qs0.w = pack2bf(aS0[2], aS0[3]);
        pr1.x = pack2bf(aP1[0] + bmv.x, aP1[1] + bmv.y);
        pr1.y = pack2bf(aR1[0] + bvv.x, aR1[1] + bvv.y);
        pr1.z = pack2bf(aP1[2] + bmv.z, aP1[3] + bmv.w);
        pr1.w = pack2bf(aR1[2] + bvv.z, aR1[3] + bvv.w);
        qs1.x = pack2bf(aQ1[0], aQ1[1]); qs1.y = pack2bf(aS1[0], aS1[1]);
        qs1.z = pack2bf(aQ1[2], aQ1[3]); qs1.w = pack2bf(aS1[2], aS1[3]);
        *reinterpret_cast<uint4*>(&PRb[(size_t)arow0 * 128 + ct * 16 + g * 4]) = pr0;
        *reinterpret_cast<uint4*>(&QSb[(size_t)arow0 * 128 + ct * 16 + g * 4]) = qs0;
        if (t1ok) {
            *reinterpret_cast<uint4*>(&PRb[(size_t)arow1 * 128 + ct * 16 + g * 4]) = pr1;
            *reinterpret_cast<uint4*>(&QSb[(size_t)arow1 * 128 + ct * 16 + g * 4]) = qs1;
        }
    }
}

// ---------------- dst-grouped edge epilogue: 2 edges/wave, pipelined ----------
__global__ __launch_bounds__(256) void edge_head3_k(
    const uint* __restrict__ PRb, const uint* __restrict__ QSb,
    const int* __restrict__ rowptr, const int* __restrict__ srclist,
    const float* __restrict__ Wm2, const float* __restrict__ Wv2,
    float2* __restrict__ tmp, int N)
{
    int gid   = blockIdx.x * 256 + threadIdx.x;
    int node  = gid >> 6;
    int lane  = gid & 63;
    int half  = lane >> 5;
    int hlane = lane & 31;
    if (node >= N) return;
    int beg = rowptr[node];
    int end = rowptr[node + 1];
    if (beg == end) return;

    uint4 qs4 = *reinterpret_cast<const uint4*>(&QSb[(size_t)node * 128 + hlane * 4]);
    float q0 = bflo(qs4.x), q1 = bfhi(qs4.x);
    float s0 = bflo(qs4.y), s1 = bfhi(qs4.y);
    float q2 = bflo(qs4.z), q3 = bfhi(qs4.z);
    float s2 = bflo(qs4.w), s3 = bfhi(qs4.w);

    float4 wm = *reinterpret_cast<const float4*>(&Wm2[hlane * 4]);
    float4 wv = *reinterpret_cast<const float4*>(&Wv2[hlane * 4]);

    int p0 = beg + half;
    int src0 = srclist[min(p0, end - 1)];
    uint4 pr_cur = *reinterpret_cast<const uint4*>(&PRb[(size_t)src0 * 128 + hlane * 4]);

    for (int base = beg; base < end; base += 2) {
        int p = base + half;
        uint4 pr_next = pr_cur;
        if (base + 2 < end) {
            int pn = base + 2 + half;
            int srcn = srclist[min(pn, end - 1)];
            pr_next = *reinterpret_cast<const uint4*>(&PRb[(size_t)srcn * 128 + hlane * 4]);
        }

        float P0 = bflo(pr_cur.x), P1 = bfhi(pr_cur.x);
        float R0 = bflo(pr_cur.y), R1 = bfhi(pr_cur.y);
        float P2 = bflo(pr_cur.z), P3 = bfhi(pr_cur.z);
        float R2 = bflo(pr_cur.w), R3 = bfhi(pr_cur.w);

        float pm = fmaf(fmaxf(P0 + q0, 0.f), wm.x,
                   fmaf(fmaxf(P1 + q1, 0.f), wm.y,
                   fmaf(fmaxf(P2 + q2, 0.f), wm.z,
                        fmaxf(P3 + q3, 0.f) * wm.w)));
        float pv = fmaf(fmaxf(R0 + s0, 0.f), wv.x,
                   fmaf(fmaxf(R1 + s1, 0.f), wv.y,
                   fmaf(fmaxf(R2 + s2, 0.f), wv.z,
                        fmaxf(R3 + s3, 0.f) * wv.w)));

        pm += __shfl_xor(pm, 16);
        pv += __shfl_xor(pv, 16);
        float c = (hlane & 16) ? pv : pm;
        c += __shfl_xor(c, 8);
        c += __shfl_xor(c, 4);
        c += __shfl_xor(c, 2);
        c += __shfl_xor(c, 1);
        float other = __shfl(c, (lane & 32) + 16);
        if (hlane == 0 && p < end) tmp[p] = make_float2(c, other);

        pr_cur = pr_next;
    }
}

// ---------------- CSR-order -> edge-order permute + bias + exp ----------------
__global__ __launch_bounds__(256) void permute_k(
    const float2* __restrict__ tmp, const int* __restrict__ invpos,
    const float* __restrict__ bm2, const float* __restrict__ bv2,
    float* __restrict__ mean_out, float* __restrict__ var_out, int E)
{
    int e = blockIdx.x * 256 + threadIdx.x;
    if (e >= E) return;
    float2 t = tmp[invpos[e]];
    mean_out[e] = t.x + bm2[0];
    var_out[e]  = expf(0.5f * (t.y + bv2[0]));
}

extern "C" void kernel_launch(void* const* d_in, const int* in_sizes, int n_in,
                              void* d_out, int out_size, void* d_ws, size_t ws_size,
                              hipStream_t stream)
{
    const float* x       = (const float*)d_in[0];
    const int*   ei      = (const int*)d_in[1];
    const float* W1_rel  = (const float*)d_in[2];
    const float* b1      = (const float*)d_in[3];
    const float* W1_root = (const float*)d_in[4];
    const float* W2_rel  = (const float*)d_in[5];
    const float* b2      = (const float*)d_in[6];
    const float* W2_root = (const float*)d_in[7];
    const float* Wm1     = (const float*)d_in[8];
    const float* bm1     = (const float*)d_in[9];
    const float* Wm2     = (const float*)d_in[10];
    const float* bm2     = (const float*)d_in[11];
    const float* Wv1     = (const float*)d_in[12];
    const float* bv1     = (const float*)d_in[13];
    const float* Wv2     = (const float*)d_in[14];
    const float* bv2     = (const float*)d_in[15];

    const int N = in_sizes[0] / NF;   // 50000
    const int E = in_sizes[1] / 2;    // 800000

    const size_t SZ16 = (size_t)N * NF * 2;       // 12.8 MB bf16 node table

    char* base = (char*)d_ws;
    uint* x_b  = (uint*)(base);
    uint* h1b  = (uint*)(base + SZ16);
    uint* AGGb = (uint*)(base + 2 * SZ16);
    uint* PRb  = (uint*)(base + SZ16);    // overlays h1b+AGGb after conv2
    uint* QSb  = (uint*)(base + 3 * SZ16);

    char* wts = base + 5 * SZ16;
    uint* wt[8];
    for (int i = 0; i < 8; ++i) wt[i] = (uint*)(wts + (size_t)i * 32768);

    char* csr = wts + 8 * 32768;
    int* deg     = (int*)(csr);
    int* rowptr  = (int*)(csr + (size_t)(N + 64) * 4);
    int* cursor  = (int*)(csr + (size_t)(N + 64) * 8);
    int* srclist = (int*)(csr + (size_t)(N + 64) * 12);
    int* invpos  = srclist + E;
    float2* tmp  = (float2*)(invpos + E);
    int* bsum    = (int*)(tmp + E);

    float* out_mean = (float*)d_out;
    float* out_var  = out_mean + E;

    dim3 blk(256);
    const int castBlocks  = (N * 64 + 255) / 256;            // 12500
    const int countBlocks = (E + 255) / 256;                 // 3125
    dim3 proGrid(castBlocks + 256 + countBlocks);            // fused prologue
    dim3 eGrid(countBlocks);
    dim3 mfmaGrid((N + 127) / 128);                          // 391
    dim3 nodeGrid((unsigned)(((size_t)N * 64 + 255) / 256)); // 12500 (1 wave/node)
    dim3 node2Grid((unsigned)((((size_t)(N + 1) / 2) * 64 + 255) / 256)); // 2 nodes/wave
    const int NB = (N + 255) / 256;                          // 196 scan blocks
    dim3 scanGrid(NB);

    W8 wp;
    wp.src[0] = W1_rel;            wp.dst[0] = wt[0];
    wp.src[1] = W1_root;           wp.dst[1] = wt[1];
    wp.src[2] = W2_rel;            wp.dst[2] = wt[2];
    wp.src[3] = W2_root;           wp.dst[3] = wt[3];
    wp.src[4] = Wm1;               wp.dst[4] = wt[4];
    wp.src[5] = Wm1 + NF * NF;     wp.dst[5] = wt[5];
    wp.src[6] = Wv1;               wp.dst[6] = wt[6];
    wp.src[7] = Wv1 + NF * NF;     wp.dst[7] = wt[7];

    // ---- memset deg, then fused prologue (x-cast | weight-pack | count)
    hipMemsetAsync(deg, 0, (size_t)N * 4, stream);
    hipLaunchKernelGGL(prologue_k, proGrid, blk, 0, stream,
                       x, x_b, N * 64, castBlocks, wp, ei, deg, E, countBlocks);

    // ---- CSR scan + fill
    hipLaunchKernelGGL(scan1_k, scanGrid, blk, 0, stream, deg, rowptr, bsum, N);
    hipLaunchKernelGGL(scan23_k, scanGrid, blk, 0, stream, bsum, rowptr, cursor, N, E);
    hipLaunchKernelGGL(fill_k, eGrid, blk, 0, stream, ei, cursor, srclist, invpos, E);

    // ---- conv1
    hipLaunchKernelGGL(agg2_k, node2Grid, blk, 0, stream, x_b, rowptr, srclist, AGGb, N);
    hipLaunchKernelGGL(dualgemm_mfma_k, mfmaGrid, blk, 0, stream,
                       AGGb, wt[0], x_b, wt[1], b1, h1b, N);

    // ---- conv2 + head fused (h2 staged in LDS; PRb overlays h1b/AGGb region)
    hipLaunchKernelGGL(agg2_k, node2Grid, blk, 0, stream, h1b, rowptr, srclist, AGGb, N);
    hipLaunchKernelGGL(conv2head_k, mfmaGrid, blk, 0, stream,
                       AGGb, wt[2], h1b, wt[3], b2,
                       wt[4], wt[5], wt[6], wt[7], bm1, bv1, PRb, QSb, N);

    // ---- dst-grouped per-edge epilogue (raw pm/pv into CSR-ordered tmp)
    hipLaunchKernelGGL(edge_head3_k, nodeGrid, blk, 0, stream,
                       PRb, QSb, rowptr, srclist, Wm2, Wv2, tmp, N);

    // ---- permute to edge order + bias + exp
    hipLaunchKernelGGL(permute_k, eGrid, blk, 0, stream,
                       tmp, invpos, bm2, bv2, out_mean, out_var, E);
}

// Round 16
// 423.291 us; speedup vs baseline: 5.2593x; 1.0395x over previous
//
#include <hip/hip_runtime.h>
#include <cstdint>

#define NF 128

typedef unsigned int uint;
typedef short bf16x8 __attribute__((ext_vector_type(8)));
typedef float f32x4  __attribute__((ext_vector_type(4)));

__device__ __forceinline__ float2 ld2(const float* p) {
    return *reinterpret_cast<const float2*>(p);
}
__device__ __forceinline__ float bflo(uint u) { return __uint_as_float(u << 16); }
__device__ __forceinline__ float bfhi(uint u) { return __uint_as_float(u & 0xffff0000u); }
__device__ __forceinline__ uint f2bf_rne(float f) {
    uint u = __float_as_uint(f);
    return (u + 0x7fffu + ((u >> 16) & 1u)) >> 16;
}
__device__ __forceinline__ uint pack2bf(float a, float b) {
    return f2bf_rne(a) | (f2bf_rne(b) << 16);
}

__device__ __forceinline__ bf16x8 ldfrag(const uint* __restrict__ tab, int idx, int kb, int g) {
    const uint4 u = *reinterpret_cast<const uint4*>(&tab[(size_t)idx * 64 + kb * 16 + g * 4]);
    union { uint4 u4; bf16x8 b; } c; c.u4 = u; return c.b;
}

// ---------------- fused prologue: x-cast | weight-pack | degree-count ----------
struct W8 {
    const float* src[8];
    uint*        dst[8];
};
__global__ __launch_bounds__(256) void prologue_k(
    const float* __restrict__ x, uint* __restrict__ x_b, int npairs, int castBlocks,
    W8 wp,
    const int* __restrict__ ei, int* __restrict__ deg, int E, int countBlocks)
{
    int b = blockIdx.x;
    if (b < castBlocks) {
        int i = b * 256 + threadIdx.x;
        if (i >= npairs) return;
        float2 v = ld2(&x[(size_t)i * 2]);
        x_b[i] = pack2bf(v.x, v.y);
    } else if (b < castBlocks + 256) {
        int wb = b - castBlocks;          // [0,256)
        int m  = wb >> 5;                 // 8 matrices
        int bx = wb & 31;
        const float* s = wp.src[m];
        uint* d = wp.dst[m];
        int idx = bx * 256 + threadIdx.x; // [0, 8192)
        int c   = idx >> 6;
        int kdw = idx & 63;
        float a  = s[(size_t)(2 * kdw)     * NF + c];
        float b2 = s[(size_t)(2 * kdw + 1) * NF + c];
        d[(size_t)c * 64 + kdw] = pack2bf(a, b2);
    } else {
        int e = (b - castBlocks - 256) * 256 + threadIdx.x;
        if (e >= E) return;
        atomicAdd(&deg[ei[E + e]], 1);
    }
}

// ---------------- CSR scan: pass 1 (block-local) ----------------
__global__ __launch_bounds__(256) void scan1_k(const int* __restrict__ deg,
                                               int* __restrict__ rowptr,
                                               int* __restrict__ bsum, int N)
{
    int i = blockIdx.x * 256 + threadIdx.x;
    int v = (i < N) ? deg[i] : 0;
    int lane = threadIdx.x & 63;
    int wid  = threadIdx.x >> 6;
    int x = v;
#pragma unroll
    for (int off = 1; off < 64; off <<= 1) {
        int y = __shfl_up(x, off);
        if (lane >= off) x += y;
    }
    __shared__ int wsum[4];
    if (lane == 63) wsum[wid] = x;
    __syncthreads();
    int wadd = 0;
#pragma unroll
    for (int w = 0; w < 4; ++w) wadd += (w < wid) ? wsum[w] : 0;
    int incl = x + wadd;
    if (i < N) rowptr[i] = incl - v;
    if (threadIdx.x == 255) bsum[blockIdx.x] = incl;
}

// ---------------- CSR scan: fused pass 2+3 ----------------
__global__ __launch_bounds__(256) void scan23_k(const int* __restrict__ bsum,
                                                int* __restrict__ rowptr,
                                                int* __restrict__ cursor, int N, int E)
{
    int tid = threadIdx.x;
    int v = (tid < blockIdx.x) ? bsum[tid] : 0;   // NB <= 256
    int lane = tid & 63;
    int wid  = tid >> 6;
#pragma unroll
    for (int off = 32; off > 0; off >>= 1) v += __shfl_xor(v, off);
    __shared__ int ws[4];
    if (lane == 0) ws[wid] = v;
    __syncthreads();
    int prefix = ws[0] + ws[1] + ws[2] + ws[3];

    if (blockIdx.x == 0 && tid == 0) rowptr[N] = E;
    int i = blockIdx.x * 256 + tid;
    if (i >= N) return;
    int r = rowptr[i] + prefix;
    rowptr[i] = r;
    cursor[i] = r;
}

__global__ __launch_bounds__(256) void fill_k(const int* __restrict__ ei,
                                              int* __restrict__ cursor,
                                              int* __restrict__ srclist,
                                              int* __restrict__ invpos, int E)
{
    int e = blockIdx.x * 256 + threadIdx.x;
    if (e >= E) return;
    int s = ei[e];
    int d = ei[E + e];
    int pos = atomicAdd(&cursor[d], 1);
    srclist[pos] = s;
    invpos[e] = pos;
}

// ---------------- aggregation: 4 nodes/wave, 16 lanes each, uint4 gathers -----
// lane covers dwords qlane*4..qlane*4+3 (dims 8*qlane..8*qlane+7).
// even edges -> a[], odd edges -> b[]; per-dim sum order identical to agg2.
__global__ __launch_bounds__(256) void agg4_k(const uint* __restrict__ Xb,
                                              const int* __restrict__ rowptr,
                                              const int* __restrict__ srclist,
                                              uint* __restrict__ AGGb, int N)
{
    int gid   = blockIdx.x * 256 + threadIdx.x;
    int wave  = gid >> 6;
    int lane  = gid & 63;
    int q     = lane >> 4;     // quarter 0..3
    int qlane = lane & 15;     // 0..15
    int node  = wave * 4 + q;
    int nc    = min(node, N - 1);
    int beg = rowptr[nc];
    int end = rowptr[nc + 1];
    if (node >= N) { beg = 0; end = 0; }

    float a0=0.f,a1=0.f,a2=0.f,a3=0.f,a4=0.f,a5=0.f,a6=0.f,a7=0.f;
    float b0=0.f,b1=0.f,b2=0.f,b3=0.f,b4=0.f,b5=0.f,b6=0.f,b7=0.f;

    uint4 w0 = make_uint4(0,0,0,0), w1 = make_uint4(0,0,0,0);
    int ok1 = 0;
    if (beg < end) {
        int s0 = srclist[beg];
        ok1 = (beg + 1 < end);
        int s1 = ok1 ? srclist[beg + 1] : s0;
        w0 = *reinterpret_cast<const uint4*>(&Xb[(size_t)s0 * 64 + qlane * 4]);
        w1 = *reinterpret_cast<const uint4*>(&Xb[(size_t)s1 * 64 + qlane * 4]);
    }
    for (int j = beg; j < end; j += 2) {
        int jn = j + 2;
        uint4 nw0 = w0, nw1 = w1;
        int nok1 = 0;
        if (jn < end) {
            int s0 = srclist[jn];
            nok1 = (jn + 1 < end);
            int s1 = nok1 ? srclist[jn + 1] : s0;
            nw0 = *reinterpret_cast<const uint4*>(&Xb[(size_t)s0 * 64 + qlane * 4]);
            nw1 = *reinterpret_cast<const uint4*>(&Xb[(size_t)s1 * 64 + qlane * 4]);
        }
        a0 += bflo(w0.x); a1 += bfhi(w0.x); a2 += bflo(w0.y); a3 += bfhi(w0.y);
        a4 += bflo(w0.z); a5 += bfhi(w0.z); a6 += bflo(w0.w); a7 += bfhi(w0.w);
        if (ok1) {
            b0 += bflo(w1.x); b1 += bfhi(w1.x); b2 += bflo(w1.y); b3 += bfhi(w1.y);
            b4 += bflo(w1.z); b5 += bfhi(w1.z); b6 += bflo(w1.w); b7 += bfhi(w1.w);
        }
        w0 = nw0; w1 = nw1; ok1 = nok1;
    }
    if (node < N) {
        uint4 o;
        o.x = pack2bf(a0 + b0, a1 + b1);
        o.y = pack2bf(a2 + b2, a3 + b3);
        o.z = pack2bf(a4 + b4, a5 + b5);
        o.w = pack2bf(a6 + b6, a7 + b7);
        *reinterpret_cast<uint4*>(&AGGb[(size_t)node * 64 + qlane * 4]) = o;
    }
}

// ---------------- MFMA dual GEMM, 32 rows/wave (conv1; writes global) ---------
__global__ __launch_bounds__(256) void dualgemm_mfma_k(
    const uint* __restrict__ Aa, const uint* __restrict__ WaT,
    const uint* __restrict__ Ab, const uint* __restrict__ WbT,
    const float* __restrict__ bias, uint* __restrict__ C, int Nrows)
{
    const int lane = threadIdx.x & 63;
    const int wid  = threadIdx.x >> 6;
    const int g    = lane >> 4;
    const int r15  = lane & 15;
    const int rowBase = blockIdx.x * 128 + wid * 32;
    if (rowBase >= Nrows) return;
    const int arow0 = rowBase + r15;
    const int t1ok  = (rowBase + 16) < Nrows;
    const int arow1 = t1ok ? (rowBase + 16 + r15) : arow0;

    bf16x8 ba0[4], bb0[4], ba1[4], bb1[4];
#pragma unroll
    for (int kb = 0; kb < 4; ++kb) {
        ba0[kb] = ldfrag(Aa, arow0, kb, g);
        bb0[kb] = ldfrag(Ab, arow0, kb, g);
        ba1[kb] = ldfrag(Aa, arow1, kb, g);
        bb1[kb] = ldfrag(Ab, arow1, kb, g);
    }

#pragma unroll
    for (int ct = 0; ct < 8; ++ct) {
        const int wcol = ct * 16 + r15;
        f32x4 a0 = {0.f, 0.f, 0.f, 0.f};
        f32x4 a1 = {0.f, 0.f, 0.f, 0.f};
#pragma unroll
        for (int kb = 0; kb < 4; ++kb) {
            bf16x8 wf = ldfrag(WaT, wcol, kb, g);
            a0 = __builtin_amdgcn_mfma_f32_16x16x32_bf16(wf, ba0[kb], a0, 0, 0, 0);
            a1 = __builtin_amdgcn_mfma_f32_16x16x32_bf16(wf, ba1[kb], a1, 0, 0, 0);
        }
#pragma unroll
        for (int kb = 0; kb < 4; ++kb) {
            bf16x8 wf = ldfrag(WbT, wcol, kb, g);
            a0 = __builtin_amdgcn_mfma_f32_16x16x32_bf16(wf, bb0[kb], a0, 0, 0, 0);
            a1 = __builtin_amdgcn_mfma_f32_16x16x32_bf16(wf, bb1[kb], a1, 0, 0, 0);
        }

        const int colBase = ct * 16 + g * 4;
        float4 bs = *reinterpret_cast<const float4*>(&bias[colBase]);
        uint2 pk0, pk1;
        pk0.x = pack2bf(fmaxf(a0[0] + bs.x, 0.f), fmaxf(a0[1] + bs.y, 0.f));
        pk0.y = pack2bf(fmaxf(a0[2] + bs.z, 0.f), fmaxf(a0[3] + bs.w, 0.f));
        pk1.x = pack2bf(fmaxf(a1[0] + bs.x, 0.f), fmaxf(a1[1] + bs.y, 0.f));
        pk1.y = pack2bf(fmaxf(a1[2] + bs.z, 0.f), fmaxf(a1[3] + bs.w, 0.f));
        *reinterpret_cast<uint2*>(&C[(size_t)arow0 * 64 + ct * 8 + g * 2]) = pk0;
        if (t1ok)
            *reinterpret_cast<uint2*>(&C[(size_t)arow1 * 64 + ct * 8 + g * 2]) = pk1;
    }
}

// ---------------- fused conv2 + head: h2 staged in LDS ------------------------
#define LROW 72   // padded LDS row stride in dwords (16B-aligned rows, bank-spread)
__global__ __launch_bounds__(256) void conv2head_k(
    const uint* __restrict__ Aa, const uint* __restrict__ WaT,
    const uint* __restrict__ Ab, const uint* __restrict__ WbT,
    const float* __restrict__ bias,
    const uint* __restrict__ WPt, const uint* __restrict__ WQt,
    const uint* __restrict__ WRt, const uint* __restrict__ WSt,
    const float* __restrict__ bm1, const float* __restrict__ bv1,
    uint* __restrict__ PRb, uint* __restrict__ QSb, int Nrows)
{
    __shared__ uint h2s[128 * LROW];   // 36864 B

    const int lane = threadIdx.x & 63;
    const int wid  = threadIdx.x >> 6;
    const int g    = lane >> 4;
    const int r15  = lane & 15;
    const int rowBase = blockIdx.x * 128 + wid * 32;
    const int active = rowBase < Nrows;
    const int arow0 = rowBase + r15;
    const int t1ok  = active && ((rowBase + 16) < Nrows);
    const int arow1 = t1ok ? (rowBase + 16 + r15) : (active ? arow0 : 0);
    const int lrow0 = wid * 32 + r15;
    const int lrow1 = wid * 32 + 16 + r15;

    // ---- phase 1: conv2 dual GEMM -> LDS (packed bf16, same values as before)
    if (active) {
        bf16x8 ba0[4], bb0[4], ba1[4], bb1[4];
#pragma unroll
        for (int kb = 0; kb < 4; ++kb) {
            ba0[kb] = ldfrag(Aa, arow0, kb, g);
            bb0[kb] = ldfrag(Ab, arow0, kb, g);
            ba1[kb] = ldfrag(Aa, arow1, kb, g);
            bb1[kb] = ldfrag(Ab, arow1, kb, g);
        }
#pragma unroll
        for (int ct = 0; ct < 8; ++ct) {
            const int wcol = ct * 16 + r15;
            f32x4 a0 = {0.f, 0.f, 0.f, 0.f};
            f32x4 a1 = {0.f, 0.f, 0.f, 0.f};
#pragma unroll
            for (int kb = 0; kb < 4; ++kb) {
                bf16x8 wf = ldfrag(WaT, wcol, kb, g);
                a0 = __builtin_amdgcn_mfma_f32_16x16x32_bf16(wf, ba0[kb], a0, 0, 0, 0);
                a1 = __builtin_amdgcn_mfma_f32_16x16x32_bf16(wf, ba1[kb], a1, 0, 0, 0);
            }
#pragma unroll
            for (int kb = 0; kb < 4; ++kb) {
                bf16x8 wf = ldfrag(WbT, wcol, kb, g);
                a0 = __builtin_amdgcn_mfma_f32_16x16x32_bf16(wf, bb0[kb], a0, 0, 0, 0);
                a1 = __builtin_amdgcn_mfma_f32_16x16x32_bf16(wf, bb1[kb], a1, 0, 0, 0);
            }
            const int colBase = ct * 16 + g * 4;
            float4 bs = *reinterpret_cast<const float4*>(&bias[colBase]);
            uint2 pk0, pk1;
            pk0.x = pack2bf(fmaxf(a0[0] + bs.x, 0.f), fmaxf(a0[1] + bs.y, 0.f));
            pk0.y = pack2bf(fmaxf(a0[2] + bs.z, 0.f), fmaxf(a0[3] + bs.w, 0.f));
            pk1.x = pack2bf(fmaxf(a1[0] + bs.x, 0.f), fmaxf(a1[1] + bs.y, 0.f));
            pk1.y = pack2bf(fmaxf(a1[2] + bs.z, 0.f), fmaxf(a1[3] + bs.w, 0.f));
            *reinterpret_cast<uint2*>(&h2s[lrow0 * LROW + ct * 8 + g * 2]) = pk0;
            *reinterpret_cast<uint2*>(&h2s[lrow1 * LROW + ct * 8 + g * 2]) = pk1;
        }
    }
    __syncthreads();

    // ---- phase 2: head GEMM from LDS
    if (!active) return;
    bf16x8 hb0[4], hb1[4];
#pragma unroll
    for (int kb = 0; kb < 4; ++kb) {
        union { uint4 u4; bf16x8 b; } c0, c1;
        c0.u4 = *reinterpret_cast<const uint4*>(&h2s[lrow0 * LROW + kb * 16 + g * 4]);
        c1.u4 = *reinterpret_cast<const uint4*>(&h2s[lrow1 * LROW + kb * 16 + g * 4]);
        hb0[kb] = c0.b;
        hb1[kb] = c1.b;
    }

#pragma unroll
    for (int ct = 0; ct < 8; ++ct) {
        const int wcol = ct * 16 + r15;
        f32x4 aP0 = {0.f,0.f,0.f,0.f}, aQ0 = {0.f,0.f,0.f,0.f};
        f32x4 aR0 = {0.f,0.f,0.f,0.f}, aS0 = {0.f,0.f,0.f,0.f};
        f32x4 aP1 = {0.f,0.f,0.f,0.f}, aQ1 = {0.f,0.f,0.f,0.f};
        f32x4 aR1 = {0.f,0.f,0.f,0.f}, aS1 = {0.f,0.f,0.f,0.f};
#pragma unroll
        for (int kb = 0; kb < 4; ++kb) {
            bf16x8 wP = ldfrag(WPt, wcol, kb, g);
            bf16x8 wQ = ldfrag(WQt, wcol, kb, g);
            bf16x8 wR = ldfrag(WRt, wcol, kb, g);
            bf16x8 wS = ldfrag(WSt, wcol, kb, g);
            aP0 = __builtin_amdgcn_mfma_f32_16x16x32_bf16(wP, hb0[kb], aP0, 0, 0, 0);
            aP1 = __builtin_amdgcn_mfma_f32_16x16x32_bf16(wP, hb1[kb], aP1, 0, 0, 0);
            aQ0 = __builtin_amdgcn_mfma_f32_16x16x32_bf16(wQ, hb0[kb], aQ0, 0, 0, 0);
            aQ1 = __builtin_amdgcn_mfma_f32_16x16x32_bf16(wQ, hb1[kb], aQ1, 0, 0, 0);
            aR0 = __builtin_amdgcn_mfma_f32_16x16x32_bf16(wR, hb0[kb], aR0, 0, 0, 0);
            aR1 = __builtin_amdgcn_mfma_f32_16x16x32_bf16(wR, hb1[kb], aR1, 0, 0, 0);
            aS0 = __builtin_amdgcn_mfma_f32_16x16x32_bf16(wS, hb0[kb], aS0, 0, 0, 0);
            aS1 = __builtin_amdgcn_mfma_f32_16x16x32_bf16(wS, hb1[kb], aS1, 0, 0, 0);
        }
        const int colBase = ct * 16 + g * 4;
        float4 bmv = *reinterpret_cast<const float4*>(&bm1[colBase]);
        float4 bvv = *reinterpret_cast<const float4*>(&bv1[colBase]);
        uint4 pr0, qs0, pr1, qs1;
        pr0.x = pack2bf(aP0[0] + bmv.x, aP0[1] + bmv.y);
        pr0.y = pack2bf(aR0[0] + bvv.x, aR0[1] + bvv.y);
        pr0.z = pack2bf(aP0[2] + bmv.z, aP0[3] + bmv.w);
        pr0.w = pack2bf(aR0[2] + bvv.z, aR0[3] + bvv.w);
        qs0.x = pack2bf(aQ0[0], aQ0[1]); qs0.y = pack2bf(aS0[0], aS0[1]);
        qs0.z = pack2bf(aQ0[2], aQ0[3]); qs0.w = pack2bf(aS0[2], aS0[3]);
        pr1.x = pack2bf(aP1[0] + bmv.x, aP1[1] + bmv.y);
        pr1.y = pack2bf(aR1[0] + bvv.x, aR1[1] + bvv.y);
        pr1.z = pack2bf(aP1[2] + bmv.z, aP1[3] + bmv.w);
        pr1.w = pack2bf(aR1[2] + bvv.z, aR1[3] + bvv.w);
        qs1.x = pack2bf(aQ1[0], aQ1[1]); qs1.y = pack2bf(aS1[0], aS1[1]);
        qs1.z = pack2bf(aQ1[2], aQ1[3]); qs1.w = pack2bf(aS1[2], aS1[3]);
        *reinterpret_cast<uint4*>(&PRb[(size_t)arow0 * 128 + ct * 16 + g * 4]) = pr0;
        *reinterpret_cast<uint4*>(&QSb[(size_t)arow0 * 128 + ct * 16 + g * 4]) = qs0;
        if (t1ok) {
            *reinterpret_cast<uint4*>(&PRb[(size_t)arow1 * 128 + ct * 16 + g * 4]) = pr1;
            *reinterpret_cast<uint4*>(&QSb[(size_t)arow1 * 128 + ct * 16 + g * 4]) = qs1;
        }
    }
}

// ---------------- dst-grouped edge epilogue: 2 edges/wave, pipelined ----------
__global__ __launch_bounds__(256) void edge_head3_k(
    const uint* __restrict__ PRb, const uint* __restrict__ QSb,
    const int* __restrict__ rowptr, const int* __restrict__ srclist,
    const float* __restrict__ Wm2, const float* __restrict__ Wv2,
    float2* __restrict__ tmp, int N)
{
    int gid   = blockIdx.x * 256 + threadIdx.x;
    int node  = gid >> 6;
    int lane  = gid & 63;
    int half  = lane >> 5;
    int hlane = lane & 31;
    if (node >= N) return;
    int beg = rowptr[node];
    int end = rowptr[node + 1];
    if (beg == end) return;

    uint4 qs4 = *reinterpret_cast<const uint4*>(&QSb[(size_t)node * 128 + hlane * 4]);
    float q0 = bflo(qs4.x), q1 = bfhi(qs4.x);
    float s0 = bflo(qs4.y), s1 = bfhi(qs4.y);
    float q2 = bflo(qs4.z), q3 = bfhi(qs4.z);
    float s2 = bflo(qs4.w), s3 = bfhi(qs4.w);

    float4 wm = *reinterpret_cast<const float4*>(&Wm2[hlane * 4]);
    float4 wv = *reinterpret_cast<const float4*>(&Wv2[hlane * 4]);

    int p0 = beg + half;
    int src0 = srclist[min(p0, end - 1)];
    uint4 pr_cur = *reinterpret_cast<const uint4*>(&PRb[(size_t)src0 * 128 + hlane * 4]);

    for (int base = beg; base < end; base += 2) {
        int p = base + half;
        uint4 pr_next = pr_cur;
        if (base + 2 < end) {
            int pn = base + 2 + half;
            int srcn = srclist[min(pn, end - 1)];
            pr_next = *reinterpret_cast<const uint4*>(&PRb[(size_t)srcn * 128 + hlane * 4]);
        }

        float P0 = bflo(pr_cur.x), P1 = bfhi(pr_cur.x);
        float R0 = bflo(pr_cur.y), R1 = bfhi(pr_cur.y);
        float P2 = bflo(pr_cur.z), P3 = bfhi(pr_cur.z);
        float R2 = bflo(pr_cur.w), R3 = bfhi(pr_cur.w);

        float pm = fmaf(fmaxf(P0 + q0, 0.f), wm.x,
                   fmaf(fmaxf(P1 + q1, 0.f), wm.y,
                   fmaf(fmaxf(P2 + q2, 0.f), wm.z,
                        fmaxf(P3 + q3, 0.f) * wm.w)));
        float pv = fmaf(fmaxf(R0 + s0, 0.f), wv.x,
                   fmaf(fmaxf(R1 + s1, 0.f), wv.y,
                   fmaf(fmaxf(R2 + s2, 0.f), wv.z,
                        fmaxf(R3 + s3, 0.f) * wv.w)));

        pm += __shfl_xor(pm, 16);
        pv += __shfl_xor(pv, 16);
        float c = (hlane & 16) ? pv : pm;
        c += __shfl_xor(c, 8);
        c += __shfl_xor(c, 4);
        c += __shfl_xor(c, 2);
        c += __shfl_xor(c, 1);
        float other = __shfl(c, (lane & 32) + 16);
        if (hlane == 0 && p < end) tmp[p] = make_float2(c, other);

        pr_cur = pr_next;
    }
}

// ---------------- CSR-order -> edge-order permute + bias + exp ----------------
__global__ __launch_bounds__(256) void permute_k(
    const float2* __restrict__ tmp, const int* __restrict__ invpos,
    const float* __restrict__ bm2, const float* __restrict__ bv2,
    float* __restrict__ mean_out, float* __restrict__ var_out, int E)
{
    int e = blockIdx.x * 256 + threadIdx.x;
    if (e >= E) return;
    float2 t = tmp[invpos[e]];
    mean_out[e] = t.x + bm2[0];
    var_out[e]  = expf(0.5f * (t.y + bv2[0]));
}

extern "C" void kernel_launch(void* const* d_in, const int* in_sizes, int n_in,
                              void* d_out, int out_size, void* d_ws, size_t ws_size,
                              hipStream_t stream)
{
    const float* x       = (const float*)d_in[0];
    const int*   ei      = (const int*)d_in[1];
    const float* W1_rel  = (const float*)d_in[2];
    const float* b1      = (const float*)d_in[3];
    const float* W1_root = (const float*)d_in[4];
    const float* W2_rel  = (const float*)d_in[5];
    const float* b2      = (const float*)d_in[6];
    const float* W2_root = (const float*)d_in[7];
    const float* Wm1     = (const float*)d_in[8];
    const float* bm1     = (const float*)d_in[9];
    const float* Wm2     = (const float*)d_in[10];
    const float* bm2     = (const float*)d_in[11];
    const float* Wv1     = (const float*)d_in[12];
    const float* bv1     = (const float*)d_in[13];
    const float* Wv2     = (const float*)d_in[14];
    const float* bv2     = (const float*)d_in[15];

    const int N = in_sizes[0] / NF;   // 50000
    const int E = in_sizes[1] / 2;    // 800000

    const size_t SZ16 = (size_t)N * NF * 2;       // 12.8 MB bf16 node table

    char* base = (char*)d_ws;
    uint* x_b  = (uint*)(base);
    uint* h1b  = (uint*)(base + SZ16);
    uint* AGGb = (uint*)(base + 2 * SZ16);
    uint* PRb  = (uint*)(base + SZ16);    // overlays h1b+AGGb after conv2
    uint* QSb  = (uint*)(base + 3 * SZ16);

    char* wts = base + 5 * SZ16;
    uint* wt[8];
    for (int i = 0; i < 8; ++i) wt[i] = (uint*)(wts + (size_t)i * 32768);

    char* csr = wts + 8 * 32768;
    int* deg     = (int*)(csr);
    int* rowptr  = (int*)(csr + (size_t)(N + 64) * 4);
    int* cursor  = (int*)(csr + (size_t)(N + 64) * 8);
    int* srclist = (int*)(csr + (size_t)(N + 64) * 12);
    int* invpos  = srclist + E;
    float2* tmp  = (float2*)(invpos + E);
    int* bsum    = (int*)(tmp + E);

    float* out_mean = (float*)d_out;
    float* out_var  = out_mean + E;

    dim3 blk(256);
    const int castBlocks  = (N * 64 + 255) / 256;            // 12500
    const int countBlocks = (E + 255) / 256;                 // 3125
    dim3 proGrid(castBlocks + 256 + countBlocks);            // fused prologue
    dim3 eGrid(countBlocks);
    dim3 mfmaGrid((N + 127) / 128);                          // 391
    dim3 nodeGrid((unsigned)(((size_t)N * 64 + 255) / 256)); // 12500 (1 wave/node)
    dim3 node4Grid((unsigned)((((size_t)(N + 3) / 4) * 64 + 255) / 256)); // 4 nodes/wave
    const int NB = (N + 255) / 256;                          // 196 scan blocks
    dim3 scanGrid(NB);

    W8 wp;
    wp.src[0] = W1_rel;            wp.dst[0] = wt[0];
    wp.src[1] = W1_root;           wp.dst[1] = wt[1];
    wp.src[2] = W2_rel;            wp.dst[2] = wt[2];
    wp.src[3] = W2_root;           wp.dst[3] = wt[3];
    wp.src[4] = Wm1;               wp.dst[4] = wt[4];
    wp.src[5] = Wm1 + NF * NF;     wp.dst[5] = wt[5];
    wp.src[6] = Wv1;               wp.dst[6] = wt[6];
    wp.src[7] = Wv1 + NF * NF;     wp.dst[7] = wt[7];

    // ---- memset deg, then fused prologue (x-cast | weight-pack | count)
    hipMemsetAsync(deg, 0, (size_t)N * 4, stream);
    hipLaunchKernelGGL(prologue_k, proGrid, blk, 0, stream,
                       x, x_b, N * 64, castBlocks, wp, ei, deg, E, countBlocks);

    // ---- CSR scan + fill
    hipLaunchKernelGGL(scan1_k, scanGrid, blk, 0, stream, deg, rowptr, bsum, N);
    hipLaunchKernelGGL(scan23_k, scanGrid, blk, 0, stream, bsum, rowptr, cursor, N, E);
    hipLaunchKernelGGL(fill_k, eGrid, blk, 0, stream, ei, cursor, srclist, invpos, E);

    // ---- conv1
    hipLaunchKernelGGL(agg4_k, node4Grid, blk, 0, stream, x_b, rowptr, srclist, AGGb, N);
    hipLaunchKernelGGL(dualgemm_mfma_k, mfmaGrid, blk, 0, stream,
                       AGGb, wt[0], x_b, wt[1], b1, h1b, N);

    // ---- conv2 + head fused (h2 staged in LDS; PRb overlays h1b/AGGb region)
    hipLaunchKernelGGL(agg4_k, node4Grid, blk, 0, stream, h1b, rowptr, srclist, AGGb, N);
    hipLaunchKernelGGL(conv2head_k, mfmaGrid, blk, 0, stream,
                       AGGb, wt[2], h1b, wt[3], b2,
                       wt[4], wt[5], wt[6], wt[7], bm1, bv1, PRb, QSb, N);

    // ---- dst-grouped per-edge epilogue (raw pm/pv into CSR-ordered tmp)
    hipLaunchKernelGGL(edge_head3_k, nodeGrid, blk, 0, stream,
                       PRb, QSb, rowptr, srclist, Wm2, Wv2, tmp, N);

    // ---- permute to edge order + bias + exp
    hipLaunchKernelGGL(permute_k, eGrid, blk, 0, stream,
                       tmp, invpos, bm2, bv2, out_mean, out_var, E);
}